// Round 3
// baseline (261.485 us; speedup 1.0000x reference)
//
#include <hip/hip_runtime.h>

#define BSZ 32768
#define TT  3
#define OO  16
#define RESCUE_THR 2.5e-3f  // f16 2-pass logit sigma ~2.7e-4; thr ~6.5 sigma of gap err

typedef __attribute__((ext_vector_type(8))) _Float16 f16x8;
typedef __attribute__((ext_vector_type(4))) _Float16 f16x4;
typedef __attribute__((ext_vector_type(4))) float f32x4;

__device__ __forceinline__ unsigned short f2h(float f) {
  return __builtin_bit_cast(unsigned short, (_Float16)f);
}
__device__ __forceinline__ float h2f(unsigned short u) {
  return (float)__builtin_bit_cast(_Float16, u);
}
__device__ __forceinline__ unsigned pack2(unsigned short a, unsigned short b) {
  return (unsigned)a | ((unsigned)b << 16);
}

// Wf: fragment-major f16 table. [nblk=20][itg=16][lane=64][j=8], element =
// W^T[n = nblk*16 + (lane&15)][k = itg*32 + (lane>>4)*8 + j].
// n<256: W1 cols; 256..303: w_gates; 304..319: zero.
// W2A/W3A: A-fragments for the 16x16x16 f16 tail MFMAs, [e][lane][j=0..3]:
//   W2A[m=lane&15][k=(lane>>4)*4+j] = (m<8) ? W2[e][k][m] : 0   (m = h2 unit)
//   W3A[m=lane&15][k=(lane>>4)*4+j] = (k<8) ? W3[e][k][m] : 0   (m = output unit)
__global__ void k_prepw(const float* __restrict__ W1, const float* __restrict__ wg,
                        const float* __restrict__ W2, const float* __restrict__ W3,
                        unsigned short* __restrict__ Wf,
                        unsigned short* __restrict__ W2A,
                        unsigned short* __restrict__ W3A, float* __restrict__ acc) {
  if (blockIdx.x == 0 && threadIdx.x < 98) acc[threadIdx.x] = 0.f;
  for (int idx = blockIdx.x * 256 + threadIdx.x; idx < 20 * 16 * 64 * 8;
       idx += gridDim.x * 256) {
    const int nblk = idx >> 13, itg = (idx >> 9) & 15;
    const int lane = (idx >> 3) & 63, j = idx & 7;
    const int n = nblk * 16 + (lane & 15);
    const int k = itg * 32 + (lane >> 4) * 8 + j;
    float v = 0.f;
    if (n < 256) v = W1[(size_t)(n >> 4) * 8192 + k * 16 + (n & 15)];
    else if (n < 304) v = wg[(size_t)((n - 256) >> 4) * 8192 + k * 16 + ((n - 256) & 15)];
    Wf[idx] = f2h(v);
  }
  const int idx2 = blockIdx.x * 256 + threadIdx.x;
  if (idx2 < 16 * 64 * 4) {
    const int e = idx2 >> 8, lane = (idx2 >> 2) & 63, j = idx2 & 3;
    const int m = lane & 15, k = (lane >> 4) * 4 + j;
    W2A[idx2] = f2h((m < 8) ? W2[e * 128 + k * 8 + m] : 0.f);
    W3A[idx2] = f2h((k < 8) ? W3[e * 128 + k * 16 + m] : 0.f);
  }
}

struct FSmem {
  union {
    struct {                            // phase a: x chunk (BK=128), frag order
      unsigned short xh[4][4][64][8];   // [m][it][lane][8] — 16 KB (f16 hi)
      unsigned short xl[4][4][64][8];   // 16 KB (f16 lo)
    } a;
    struct {                            // phase b
      union {
        float lgs[64][52];              // logits (gating), dead after top-k
        float eoL[2][16][16][16];       // [mh][r16][e][o^swz] — 32 KB
      } u2;
      float gvL[64][12];
      int   giL[64][12];
      float impL[48], loadL[48];
      int   nresc, resc[192];
      double resL[16];
    } b;
  } u;
  float rzrow[64];
};

__global__ __launch_bounds__(512, 4) void k_fused(
    const float* __restrict__ x, const unsigned short* __restrict__ Wf,
    const float* __restrict__ b1, const float* __restrict__ bg,
    const float* __restrict__ wg, const unsigned short* __restrict__ W2A,
    const float* __restrict__ b2, const unsigned short* __restrict__ W3A,
    const float* __restrict__ b3, float* __restrict__ out, float* acc_imp,
    float* acc_load, float* rz_acc, unsigned* ctr) {
  __shared__ FSmem sm;
  const int tid = threadIdx.x;
  const int b0 = blockIdx.x * 64;
  const int w = tid >> 6, l = tid & 63;
  const int l15 = l & 15, quad = l >> 4;
  const int mh = w >> 2;   // batch-col half (0: rows 0-31, 1: rows 32-63)
  const int cg = w & 3;    // n-col group (80 n each)
  const int srow = tid >> 3, skf = tid & 7;          // staging: row, float4-slot
  const int sm_abs = srow >> 4;
  const int slane = (srow & 15) + 16 * (skf >> 1);
  const int sj = (skf & 1) * 4;

  // acc holds h1^T fragments: row = n_local (quad*4+reg), col = batch (l15).
  f32x4 acc[2][5];
#pragma unroll
  for (int m = 0; m < 2; m++)
#pragma unroll
    for (int c = 0; c < 5; c++) acc[m][c] = (f32x4){0.f, 0.f, 0.f, 0.f};
  float rzsum = 0.f;

  auto woffs = [&](int itg, int c) -> size_t {
    return ((size_t)(((cg * 5 + c) * 16 + itg) * 64 + l)) * 8;
  };

  const float* xbase = &x[(size_t)(b0 + srow) * 512 + skf * 4];

#pragma unroll 1
  for (int ch = 0; ch < 4; ++ch) {
    if (ch) __syncthreads();  // protect chunk overwrite
    {
      // x loads transient within the staging phase (no cross-GEMM live regs)
      const float* xp = xbase + ch * 128;
      float4 xv[4];
#pragma unroll
      for (int r = 0; r < 4; r++) xv[r] = *(const float4*)(xp + r * 32);
#pragma unroll
      for (int r = 0; r < 4; r++) {
        const float v0 = xv[r].x, v1 = xv[r].y, v2 = xv[r].z, v3 = xv[r].w;
        rzsum += __expf(v0) + __expf(v1) + __expf(v2) + __expf(v3);
        const unsigned short h0 = f2h(v0), h1_ = f2h(v1), h2_ = f2h(v2), h3 = f2h(v3);
        uint2 ph, pl;
        ph.x = pack2(h0, h1_); ph.y = pack2(h2_, h3);
        pl.x = pack2(f2h(v0 - h2f(h0)), f2h(v1 - h2f(h1_)));
        pl.y = pack2(f2h(v2 - h2f(h2_)), f2h(v3 - h2f(h3)));
        *(uint2*)&sm.u.a.xh[sm_abs][r][slane][sj] = ph;
        *(uint2*)&sm.u.a.xl[sm_abs][r][slane][sj] = pl;
      }
    }
    __syncthreads();

    // W fragment stream, depth-1 rolling prefetch (L2-resident after block 0)
    f16x8 bh = *(const f16x8*)&Wf[woffs(ch * 4, 0)];
    f16x8 ah[2], al[2];
#pragma unroll
    for (int i = 0; i < 20; ++i) {
      const int it = i / 5, c = i % 5;
      if (c == 0) {
#pragma unroll
        for (int m = 0; m < 2; m++) {
          ah[m] = *(const f16x8*)&sm.u.a.xh[mh * 2 + m][it][l][0];
          al[m] = *(const f16x8*)&sm.u.a.xl[mh * 2 + m][it][l][0];
        }
      }
      f16x8 bhn = bh;
      if (i + 1 < 20)
        bhn = *(const f16x8*)&Wf[woffs(ch * 4 + (i + 1) / 5, (i + 1) % 5)];
      // A = W fragment, B = x fragment  ->  D = h1^T (row=n, col=batch)
#pragma unroll
      for (int m = 0; m < 2; m++) {
        acc[m][c] = __builtin_amdgcn_mfma_f32_16x16x32_f16(bh, ah[m], acc[m][c], 0, 0, 0);
        acc[m][c] = __builtin_amdgcn_mfma_f32_16x16x32_f16(bh, al[m], acc[m][c], 0, 0, 0);
      }
      bh = bhn;
    }
  }

  // ---- router-z: 8 threads share a row ----
  rzsum += __shfl_xor(rzsum, 1);
  rzsum += __shfl_xor(rzsum, 2);
  rzsum += __shfl_xor(rzsum, 4);
  if (skf == 0) sm.rzrow[srow] = rzsum;
  __syncthreads();  // also: MFMA LDS reads done, union reuse safe

  if (tid < 64) {
    float vv = __logf(sm.rzrow[tid]);
#pragma unroll
    for (int off = 32; off; off >>= 1) vv += __shfl_xor(vv, off);
    if (tid == 0) atomicAdd(rz_acc, vv);
  }
  // logits -> lgs (cg 3 holds n 240..319; c=1..3 are the 48 gate cols)
  if (cg == 3) {
#pragma unroll
    for (int c = 1; c < 4; c++) {
#pragma unroll
      for (int m = 0; m < 2; m++)
#pragma unroll
        for (int reg = 0; reg < 4; reg++) {
          const int row = 32 * mh + 16 * m + l15;
          const int cc = 16 * (c - 1) + quad * 4 + reg;
          sm.u.b.u2.lgs[row][cc] = acc[m][c][reg] + bg[cc];
        }
    }
  }
  if (tid < 48) { sm.u.b.impL[tid] = 0.f; sm.u.b.loadL[tid] = 0.f; }
  if (tid == 0) sm.u.b.nresc = 0;
  __syncthreads();

  // ---- gating: 192 threads = 3 tasks x 64 rows (masked top-k) ----
  if (tid < 192) {
    const int r = tid & 63, tk = tid >> 6;
    float v[16];
#pragma unroll
    for (int e = 0; e < 16; e++) v[e] = sm.u.b.u2.lgs[r][tk * 16 + e];
    unsigned used = 0;
    int idx[5]; float val[5];
#pragma unroll
    for (int p = 0; p < 5; p++) {
      float best = -INFINITY; int bi = 0;
#pragma unroll
      for (int e = 0; e < 16; e++) {
        const float ve = ((used >> e) & 1u) ? -INFINITY : v[e];
        if (ve > best) { best = ve; bi = e; }
      }
      idx[p] = bi; val[p] = best; used |= 1u << bi;
    }
    if (val[3] - val[4] < RESCUE_THR) {
      const int s = atomicAdd(&sm.u.b.nresc, 1);
      sm.u.b.resc[s] = (r << 2) | tk;
    }
    const float m = val[0];
    float ex[4], sum = 0.f;
#pragma unroll
    for (int p = 0; p < 4; p++) { ex[p] = __expf(val[p] - m); sum += ex[p]; }
#pragma unroll
    for (int p = 0; p < 4; p++) {
      const float g = ex[p] / sum;
      sm.u.b.gvL[r][tk * 4 + p] = g;
      sm.u.b.giL[r][tk * 4 + p] = idx[p];
      atomicAdd(&sm.u.b.impL[tk * 16 + idx[p]], g);
      atomicAdd(&sm.u.b.loadL[tk * 16 + idx[p]], 1.f);
    }
  }
  __syncthreads();

  // ---- cooperative f64 rescue for near-ties ----
  const int nr = sm.u.b.nresc;
  for (int i = 0; i < nr; i++) {
    const int st = sm.u.b.resc[i];
    const int r = st >> 2, tk = st & 3;
    if (tid < 256) {
      const int e = tid >> 4, part = tid & 15;
      const float* xr2 = &x[(size_t)(b0 + r) * 512];
      const float* wgc = &wg[(size_t)tk * 8192 + e];
      double a = 0.0;
      for (int d = part * 32; d < part * 32 + 32; d++)
        a += (double)xr2[d] * (double)wgc[(size_t)d * 16];
#pragma unroll
      for (int off = 1; off < 16; off <<= 1) a += __shfl_xor(a, off);
      if (part == 0) sm.u.b.resL[e] = a + (double)bg[tk * 16 + e];
    }
    __syncthreads();
    if (tid == 0) {
      for (int p = 0; p < 4; p++) {
        sm.u.b.impL[tk * 16 + sm.u.b.giL[r][tk * 4 + p]] -= sm.u.b.gvL[r][tk * 4 + p];
        sm.u.b.loadL[tk * 16 + sm.u.b.giL[r][tk * 4 + p]] -= 1.f;
      }
      unsigned used = 0;
      int idx[4]; float val[4];
      for (int p = 0; p < 4; p++) {
        double best = -1e300; int bi = 0;
        for (int e2 = 0; e2 < 16; e2++) {
          if ((used >> e2) & 1u) continue;
          const double ve = sm.u.b.resL[e2];
          if (ve > best) { best = ve; bi = e2; }
        }
        idx[p] = bi; val[p] = (float)best; used |= 1u << bi;
      }
      const float m = val[0];
      float ex[4], sum = 0.f;
      for (int p = 0; p < 4; p++) { ex[p] = __expf(val[p] - m); sum += ex[p]; }
      for (int p = 0; p < 4; p++) {
        const float g = ex[p] / sum;
        sm.u.b.gvL[r][tk * 4 + p] = g;
        sm.u.b.giL[r][tk * 4 + p] = idx[p];
        sm.u.b.impL[tk * 16 + idx[p]] += g;
        sm.u.b.loadL[tk * 16 + idx[p]] += 1.f;
      }
    }
    __syncthreads();
  }
  if (tid < 48) {
    atomicAdd(&acc_imp[tid], sm.u.b.impL[tid]);
    atomicAdd(&acc_load[tid], sm.u.b.loadL[tid]);
  }

  // ---- MFMA expert tail + combine: 2 passes of 32 rows ----
  // acc[m][c] (bias+relu, f16) is directly the B-operand (col=batch l15,
  // k=n_local=quad*4+reg) of 16x16x16 f16 MFMAs with W2A/W3A as A.
  const int nexp = (cg < 3) ? 5 : 1;  // cg==3 owns only expert 15 (c=0)
#pragma unroll 1
  for (int m = 0; m < 2; ++m) {
    if (m) __syncthreads();  // prev combine reads done before eoL overwrite
#pragma unroll
    for (int c = 0; c < 5; ++c) {
      if (c < nexp) {
        const int e = 5 * cg + c;
        const f32x4 b1v = *(const f32x4*)&b1[(e << 4) + quad * 4];
        f16x4 h1f;
#pragma unroll
        for (int r = 0; r < 4; r++)
          h1f[r] = (_Float16)fmaxf(acc[m][c][r] + b1v[r], 0.f);
        const f16x4 w2 = *(const f16x4*)&W2A[((size_t)e * 64 + l) * 4];
        f32x4 h2 = (quad < 2) ? *(const f32x4*)&b2[e * 8 + quad * 4]
                              : (f32x4){0.f, 0.f, 0.f, 0.f};
        h2 = __builtin_amdgcn_mfma_f32_16x16x16f16(w2, h1f, h2, 0, 0, 0);
        f16x4 h2q;
#pragma unroll
        for (int r = 0; r < 4; r++) h2q[r] = (_Float16)fmaxf(h2[r], 0.f);
        const f16x4 w3 = *(const f16x4*)&W3A[((size_t)e * 64 + l) * 4];
        f32x4 eo = *(const f32x4*)&b3[(e << 4) + quad * 4];
        eo = __builtin_amdgcn_mfma_f32_16x16x16f16(w3, h2q, eo, 0, 0, 0);
#pragma unroll
        for (int r = 0; r < 4; r++) eo[r] = fmaxf(eo[r], 0.f);
        // eo^T frag: row=o=quad*4+r, col=batch=l15. XOR-swizzle o-slot by row.
        *(f32x4*)&sm.u.b.u2.eoL[mh][l15][e][(quad * 4) ^ ((l15 & 3) << 2)] = eo;
      }
    }
    __syncthreads();
    {  // combine: 512 threads = 32 rows x 16 outputs
      const int rid = tid >> 4, o = tid & 15;
      const int mh_r = rid >> 4, r16 = rid & 15;
      const int rl = 32 * mh_r + 16 * m + r16;
      const int osw = (r16 & 3) << 2;
#pragma unroll
      for (int tk = 0; tk < TT; tk++) {
        float y = 0.f;
#pragma unroll
        for (int p = 0; p < 4; p++)
          y += sm.u.b.gvL[rl][tk * 4 + p] *
               sm.u.b.u2.eoL[mh_r][r16][sm.u.b.giL[rl][tk * 4 + p]][o ^ osw];
        out[((size_t)tk * BSZ + b0 + rl) * OO + o] = y;
      }
    }
  }

  // ---- merged k_final: last block computes lb/rz tail ----
  __syncthreads();
  if (tid == 0) {
    __threadfence();
    const unsigned done = atomicAdd(ctr, 1u);
    if (done == gridDim.x - 1) {
      __threadfence();
      double lb = 0.0;
      for (int t = 0; t < TT; t++) {
        const float* imp = &acc_imp[t * 16];
        const float* ld = &acc_load[t * 16];
        double si = 0, sl = 0, dot = 0;
        for (int e2 = 0; e2 < 16; e2++) {
          si += imp[e2]; sl += ld[e2]; dot += (double)imp[e2] * ld[e2];
        }
        const double mi = si / 16.0, ml = sl / 16.0;
        double vi = 0, vl = 0;
        for (int e2 = 0; e2 < 16; e2++) {
          const double di = imp[e2] - mi, dl = ld[e2] - ml;
          vi += di * di; vl += dl * dl;
        }
        vi /= 15.0; vl /= 15.0;
        lb += (vi / (mi * mi + 1e-10) + vl / (ml * ml + 1e-10)) * 0.01
            + 16.0 * dot / (double)BSZ * 0.01;
      }
      float* out_tail = out + (size_t)TT * BSZ * OO;
      out_tail[0] = (float)lb;
      out_tail[1] = (float)(3.0 * (rz_acc[0] / (double)BSZ) * 0.001);
    }
  }
}

extern "C" void kernel_launch(void* const* d_in, const int* in_sizes, int n_in,
                              void* d_out, int out_size, void* d_ws, size_t ws_size,
                              hipStream_t stream) {
  const float* x  = (const float*)d_in[0];
  const float* wg = (const float*)d_in[1];
  const float* bg = (const float*)d_in[2];
  const float* W1 = (const float*)d_in[3];
  const float* b1 = (const float*)d_in[4];
  const float* W2 = (const float*)d_in[5];
  const float* b2 = (const float*)d_in[6];
  const float* W3 = (const float*)d_in[7];
  const float* b3 = (const float*)d_in[8];
  float* out = (float*)d_out;

  char* wsb = (char*)d_ws;
  unsigned short* Wf  = (unsigned short*)wsb;            // 327,680 B
  unsigned short* W2A = (unsigned short*)(wsb + 327680); // 8,192 B
  unsigned short* W3A = (unsigned short*)(wsb + 335872); // 8,192 B
  float* acc = (float*)(wsb + 344064);                   // 98 floats (incl. ctr)

  k_prepw<<<dim3(640), dim3(256), 0, stream>>>(W1, wg, W2, W3, Wf, W2A, W3A, acc);
  k_fused<<<dim3(BSZ / 64), dim3(512), 0, stream>>>(
      x, Wf, b1, bg, wg, W2A, b2, W3A, b3, out, acc, acc + 48, acc + 96,
      (unsigned*)(acc + 97));
}

// Round 5
// 244.734 us; speedup vs baseline: 1.0684x; 1.0684x over previous
//
#include <hip/hip_runtime.h>

#define BSZ 32768
#define TT  3
#define OO  16
#define RESCUE_THR 2.5e-3f  // f16 2-pass logit sigma ~2.7e-4; thr ~6.5 sigma of gap err

typedef __attribute__((ext_vector_type(8))) _Float16 f16x8;
typedef __attribute__((ext_vector_type(4))) _Float16 f16x4;
typedef __attribute__((ext_vector_type(4))) float f32x4;

__device__ __forceinline__ unsigned short f2h(float f) {
  return __builtin_bit_cast(unsigned short, (_Float16)f);
}
__device__ __forceinline__ float h2f(unsigned short u) {
  return (float)__builtin_bit_cast(_Float16, u);
}
__device__ __forceinline__ unsigned pack2(unsigned short a, unsigned short b) {
  return (unsigned)a | ((unsigned)b << 16);
}

// Wf: fragment-major f16 table. [nblk=20][itg=16][lane=64][j=8], element =
// W^T[n = nblk*16 + (lane&15)][k = itg*32 + (lane>>4)*8 + j].
// n<256: W1 cols; 256..303: w_gates; 304..319: zero.
// W2A/W3A: A-fragments for the 16x16x16 f16 tail MFMAs, [e][lane][j=0..3]:
//   W2A[m=lane&15][k=(lane>>4)*4+j] = (m<8) ? W2[e][k][m] : 0   (m = h2 unit)
//   W3A[m=lane&15][k=(lane>>4)*4+j] = (k<8) ? W3[e][k][m] : 0   (m = output unit)
__global__ void k_prepw(const float* __restrict__ W1, const float* __restrict__ wg,
                        const float* __restrict__ W2, const float* __restrict__ W3,
                        unsigned short* __restrict__ Wf,
                        unsigned short* __restrict__ W2A,
                        unsigned short* __restrict__ W3A, float* __restrict__ acc) {
  if (blockIdx.x == 0 && threadIdx.x < 97) acc[threadIdx.x] = 0.f;
  for (int idx = blockIdx.x * 256 + threadIdx.x; idx < 20 * 16 * 64 * 8;
       idx += gridDim.x * 256) {
    const int nblk = idx >> 13, itg = (idx >> 9) & 15;
    const int lane = (idx >> 3) & 63, j = idx & 7;
    const int n = nblk * 16 + (lane & 15);
    const int k = itg * 32 + (lane >> 4) * 8 + j;
    float v = 0.f;
    if (n < 256) v = W1[(size_t)(n >> 4) * 8192 + k * 16 + (n & 15)];
    else if (n < 304) v = wg[(size_t)((n - 256) >> 4) * 8192 + k * 16 + ((n - 256) & 15)];
    Wf[idx] = f2h(v);
  }
  const int idx2 = blockIdx.x * 256 + threadIdx.x;
  if (idx2 < 16 * 64 * 4) {
    const int e = idx2 >> 8, lane = (idx2 >> 2) & 63, j = idx2 & 3;
    const int m = lane & 15, k = (lane >> 4) * 4 + j;
    W2A[idx2] = f2h((m < 8) ? W2[e * 128 + k * 8 + m] : 0.f);
    W3A[idx2] = f2h((k < 8) ? W3[e * 128 + k * 16 + m] : 0.f);
  }
}

struct FSmem {
  union {
    struct {                            // phase a: x chunk (BK=128), frag order
      unsigned short xh[4][4][64][8];   // [m][it][lane][8] — 16 KB (f16 hi)
      unsigned short xl[4][4][64][8];   // 16 KB (f16 lo)
    } a;
    struct {                            // phase b
      union {
        float lgs[64][52];              // logits (gating), dead after top-k
        float eoL[2][16][16][16];       // [mh][r16][e][o^swz] — 32 KB
      } u2;
      float gvL[64][12];
      int   giL[64][12];
      float impL[48], loadL[48];
      int   nresc, resc[192];
      double resL[16];
    } b;
  } u;
  float rzrow[64];
};

__global__ __launch_bounds__(512, 4) void k_fused(
    const float* __restrict__ x, const unsigned short* __restrict__ Wf,
    const float* __restrict__ b1, const float* __restrict__ bg,
    const float* __restrict__ wg, const unsigned short* __restrict__ W2A,
    const float* __restrict__ b2, const unsigned short* __restrict__ W3A,
    const float* __restrict__ b3, float* __restrict__ out, float* acc_imp,
    float* acc_load, float* rz_acc) {
  __shared__ FSmem sm;
  const int tid = threadIdx.x;
  const int b0 = blockIdx.x * 64;
  const int w = tid >> 6, l = tid & 63;
  const int l15 = l & 15, quad = l >> 4;
  const int mh = w >> 2;   // batch-col half (0: rows 0-31, 1: rows 32-63)
  const int cg = w & 3;    // n-col group (80 n each)
  const int srow = tid >> 3, skf = tid & 7;          // staging: row, float4-slot
  const int sm_abs = srow >> 4;
  const int slane = (srow & 15) + 16 * (skf >> 1);
  const int sj = (skf & 1) * 4;

  // acc holds h1^T fragments: row = n_local (quad*4+reg), col = batch (l15).
  f32x4 acc[2][5];
#pragma unroll
  for (int m = 0; m < 2; m++)
#pragma unroll
    for (int c = 0; c < 5; c++) acc[m][c] = (f32x4){0.f, 0.f, 0.f, 0.f};
  float rzsum = 0.f;

  auto woffs = [&](int itg, int c) -> size_t {
    return ((size_t)(((cg * 5 + c) * 16 + itg) * 64 + l)) * 8;
  };

  const float* xbase = &x[(size_t)(b0 + srow) * 512 + skf * 4];
  float4 xv[4];
#pragma unroll
  for (int r = 0; r < 4; r++) xv[r] = *(const float4*)(xbase + r * 32);

#pragma unroll 1
  for (int ch = 0; ch < 4; ++ch) {
    if (ch) __syncthreads();  // protect chunk overwrite
    {
#pragma unroll
      for (int r = 0; r < 4; r++) {
        const float v0 = xv[r].x, v1 = xv[r].y, v2 = xv[r].z, v3 = xv[r].w;
        rzsum += __expf(v0) + __expf(v1) + __expf(v2) + __expf(v3);
        const unsigned short h0 = f2h(v0), h1_ = f2h(v1), h2_ = f2h(v2), h3 = f2h(v3);
        uint2 ph, pl;
        ph.x = pack2(h0, h1_); ph.y = pack2(h2_, h3);
        pl.x = pack2(f2h(v0 - h2f(h0)), f2h(v1 - h2f(h1_)));
        pl.y = pack2(f2h(v2 - h2f(h2_)), f2h(v3 - h2f(h3)));
        *(uint2*)&sm.u.a.xh[sm_abs][r][slane][sj] = ph;
        *(uint2*)&sm.u.a.xl[sm_abs][r][slane][sj] = pl;
      }
    }
    __syncthreads();

    // W fragment stream, depth-2 rolling prefetch
    f16x8 bh0 = *(const f16x8*)&Wf[woffs(ch * 4, 0)];
    f16x8 bh1 = *(const f16x8*)&Wf[woffs(ch * 4, 1)];
    // T14: issue next chunk's x loads now; consumed after this GEMM phase
    if (ch < 3) {
#pragma unroll
      for (int r = 0; r < 4; r++)
        xv[r] = *(const float4*)(xbase + (ch + 1) * 128 + r * 32);
    }
    f16x8 ah[2], al[2];
#pragma unroll
    for (int i = 0; i < 20; ++i) {
      const int it = i / 5, c = i % 5;
      if (c == 0) {
#pragma unroll
        for (int m = 0; m < 2; m++) {
          ah[m] = *(const f16x8*)&sm.u.a.xh[mh * 2 + m][it][l][0];
          al[m] = *(const f16x8*)&sm.u.a.xl[mh * 2 + m][it][l][0];
        }
      }
      f16x8 bh2 = bh0;
      if (i + 2 < 20) bh2 = *(const f16x8*)&Wf[woffs(ch * 4 + (i + 2) / 5, (i + 2) % 5)];
      // A = W fragment, B = x fragment  ->  D = h1^T (row=n, col=batch)
#pragma unroll
      for (int m = 0; m < 2; m++) {
        acc[m][c] = __builtin_amdgcn_mfma_f32_16x16x32_f16(bh0, ah[m], acc[m][c], 0, 0, 0);
        acc[m][c] = __builtin_amdgcn_mfma_f32_16x16x32_f16(bh0, al[m], acc[m][c], 0, 0, 0);
      }
      bh0 = bh1; bh1 = bh2;
    }
  }

  // ---- router-z: 8 threads share a row ----
  rzsum += __shfl_xor(rzsum, 1);
  rzsum += __shfl_xor(rzsum, 2);
  rzsum += __shfl_xor(rzsum, 4);
  if (skf == 0) sm.rzrow[srow] = rzsum;
  __syncthreads();  // also: MFMA LDS reads done, union reuse safe

  if (tid < 64) {
    float vv = __logf(sm.rzrow[tid]);
#pragma unroll
    for (int off = 32; off; off >>= 1) vv += __shfl_xor(vv, off);
    if (tid == 0) atomicAdd(rz_acc, vv);
  }
  // logits -> lgs (cg 3 holds n 240..319; c=1..3 are the 48 gate cols)
  if (cg == 3) {
#pragma unroll
    for (int c = 1; c < 4; c++) {
#pragma unroll
      for (int m = 0; m < 2; m++)
#pragma unroll
        for (int reg = 0; reg < 4; reg++) {
          const int row = 32 * mh + 16 * m + l15;
          const int cc = 16 * (c - 1) + quad * 4 + reg;
          sm.u.b.u2.lgs[row][cc] = acc[m][c][reg] + bg[cc];
        }
    }
  }
  if (tid < 48) { sm.u.b.impL[tid] = 0.f; sm.u.b.loadL[tid] = 0.f; }
  if (tid == 0) sm.u.b.nresc = 0;
  __syncthreads();

  // ---- gating: 192 threads = 3 tasks x 64 rows (masked top-k) ----
  if (tid < 192) {
    const int r = tid & 63, tk = tid >> 6;
    float v[16];
#pragma unroll
    for (int e = 0; e < 16; e++) v[e] = sm.u.b.u2.lgs[r][tk * 16 + e];
    unsigned used = 0;
    int idx[5]; float val[5];
#pragma unroll
    for (int p = 0; p < 5; p++) {
      float best = -INFINITY; int bi = 0;
#pragma unroll
      for (int e = 0; e < 16; e++) {
        const float ve = ((used >> e) & 1u) ? -INFINITY : v[e];
        if (ve > best) { best = ve; bi = e; }
      }
      idx[p] = bi; val[p] = best; used |= 1u << bi;
    }
    if (val[3] - val[4] < RESCUE_THR) {
      const int s = atomicAdd(&sm.u.b.nresc, 1);
      sm.u.b.resc[s] = (r << 2) | tk;
    }
    const float m = val[0];
    float ex[4], sum = 0.f;
#pragma unroll
    for (int p = 0; p < 4; p++) { ex[p] = __expf(val[p] - m); sum += ex[p]; }
#pragma unroll
    for (int p = 0; p < 4; p++) {
      const float g = ex[p] / sum;
      sm.u.b.gvL[r][tk * 4 + p] = g;
      sm.u.b.giL[r][tk * 4 + p] = idx[p];
      atomicAdd(&sm.u.b.impL[tk * 16 + idx[p]], g);
      atomicAdd(&sm.u.b.loadL[tk * 16 + idx[p]], 1.f);
    }
  }
  __syncthreads();

  // ---- cooperative f64 rescue for near-ties ----
  const int nr = sm.u.b.nresc;
  for (int i = 0; i < nr; i++) {
    const int st = sm.u.b.resc[i];
    const int r = st >> 2, tk = st & 3;
    if (tid < 256) {
      const int e = tid >> 4, part = tid & 15;
      const float* xr2 = &x[(size_t)(b0 + r) * 512];
      const float* wgc = &wg[(size_t)tk * 8192 + e];
      double a = 0.0;
      for (int d = part * 32; d < part * 32 + 32; d++)
        a += (double)xr2[d] * (double)wgc[(size_t)d * 16];
#pragma unroll
      for (int off = 1; off < 16; off <<= 1) a += __shfl_xor(a, off);
      if (part == 0) sm.u.b.resL[e] = a + (double)bg[tk * 16 + e];
    }
    __syncthreads();
    if (tid == 0) {
      for (int p = 0; p < 4; p++) {
        sm.u.b.impL[tk * 16 + sm.u.b.giL[r][tk * 4 + p]] -= sm.u.b.gvL[r][tk * 4 + p];
        sm.u.b.loadL[tk * 16 + sm.u.b.giL[r][tk * 4 + p]] -= 1.f;
      }
      unsigned used = 0;
      int idx[4]; float val[4];
      for (int p = 0; p < 4; p++) {
        double best = -1e300; int bi = 0;
        for (int e2 = 0; e2 < 16; e2++) {
          if ((used >> e2) & 1u) continue;
          const double ve = sm.u.b.resL[e2];
          if (ve > best) { best = ve; bi = e2; }
        }
        idx[p] = bi; val[p] = (float)best; used |= 1u << bi;
      }
      const float m = val[0];
      float ex[4], sum = 0.f;
      for (int p = 0; p < 4; p++) { ex[p] = __expf(val[p] - m); sum += ex[p]; }
      for (int p = 0; p < 4; p++) {
        const float g = ex[p] / sum;
        sm.u.b.gvL[r][tk * 4 + p] = g;
        sm.u.b.giL[r][tk * 4 + p] = idx[p];
        sm.u.b.impL[tk * 16 + idx[p]] += g;
        sm.u.b.loadL[tk * 16 + idx[p]] += 1.f;
      }
    }
    __syncthreads();
  }
  if (tid < 48) {
    atomicAdd(&acc_imp[tid], sm.u.b.impL[tid]);
    atomicAdd(&acc_load[tid], sm.u.b.loadL[tid]);
  }

  // ---- MFMA expert tail + combine: 2 passes of 32 rows ----
  // acc[m][c] (bias+relu, f16) is directly the B-operand (col=batch l15,
  // k=n_local=quad*4+reg) of 16x16x16 f16 MFMAs with W2A/W3A as A.
  const int nexp = (cg < 3) ? 5 : 1;  // cg==3 owns only expert 15 (c=0)
#pragma unroll 1
  for (int m = 0; m < 2; ++m) {
    if (m) __syncthreads();  // prev combine reads done before eoL overwrite
#pragma unroll
    for (int c = 0; c < 5; ++c) {
      if (c < nexp) {
        const int e = 5 * cg + c;
        const f32x4 b1v = *(const f32x4*)&b1[(e << 4) + quad * 4];
        f16x4 h1f;
#pragma unroll
        for (int r = 0; r < 4; r++)
          h1f[r] = (_Float16)fmaxf(acc[m][c][r] + b1v[r], 0.f);
        const f16x4 w2 = *(const f16x4*)&W2A[((size_t)e * 64 + l) * 4];
        f32x4 h2 = (quad < 2) ? *(const f32x4*)&b2[e * 8 + quad * 4]
                              : (f32x4){0.f, 0.f, 0.f, 0.f};
        h2 = __builtin_amdgcn_mfma_f32_16x16x16f16(w2, h1f, h2, 0, 0, 0);
        f16x4 h2q;
#pragma unroll
        for (int r = 0; r < 4; r++) h2q[r] = (_Float16)fmaxf(h2[r], 0.f);
        const f16x4 w3 = *(const f16x4*)&W3A[((size_t)e * 64 + l) * 4];
        f32x4 eo = *(const f32x4*)&b3[(e << 4) + quad * 4];
        eo = __builtin_amdgcn_mfma_f32_16x16x16f16(w3, h2q, eo, 0, 0, 0);
#pragma unroll
        for (int r = 0; r < 4; r++) eo[r] = fmaxf(eo[r], 0.f);
        // eo^T frag: row=o=quad*4+r, col=batch=l15. XOR-swizzle o-slot by row.
        *(f32x4*)&sm.u.b.u2.eoL[mh][l15][e][(quad * 4) ^ ((l15 & 3) << 2)] = eo;
      }
    }
    __syncthreads();
    {  // combine: 512 threads = 32 rows x 16 outputs
      const int rid = tid >> 4, o = tid & 15;
      const int mh_r = rid >> 4, r16 = rid & 15;
      const int rl = 32 * mh_r + 16 * m + r16;
      const int osw = (r16 & 3) << 2;
#pragma unroll
      for (int tk = 0; tk < TT; tk++) {
        float y = 0.f;
#pragma unroll
        for (int p = 0; p < 4; p++)
          y += sm.u.b.gvL[rl][tk * 4 + p] *
               sm.u.b.u2.eoL[mh_r][r16][sm.u.b.giL[rl][tk * 4 + p]][o ^ osw];
        out[((size_t)tk * BSZ + b0 + rl) * OO + o] = y;
      }
    }
  }
}

__global__ void k_final(const float* __restrict__ acc_imp,
                        const float* __restrict__ acc_load,
                        const float* __restrict__ rz_acc,
                        float* __restrict__ out_tail) {
  if (threadIdx.x == 0 && blockIdx.x == 0) {
    double lb = 0.0;
    for (int t = 0; t < TT; t++) {
      const float* imp = &acc_imp[t * 16];
      const float* ld = &acc_load[t * 16];
      double si = 0, sl = 0, dot = 0;
      for (int e2 = 0; e2 < 16; e2++) {
        si += imp[e2]; sl += ld[e2]; dot += (double)imp[e2] * ld[e2];
      }
      const double mi = si / 16.0, ml = sl / 16.0;
      double vi = 0, vl = 0;
      for (int e2 = 0; e2 < 16; e2++) {
        const double di = imp[e2] - mi, dl = ld[e2] - ml;
        vi += di * di; vl += dl * dl;
      }
      vi /= 15.0; vl /= 15.0;
      lb += (vi / (mi * mi + 1e-10) + vl / (ml * ml + 1e-10)) * 0.01
          + 16.0 * dot / (double)BSZ * 0.01;
    }
    out_tail[0] = (float)lb;
    out_tail[1] = (float)(3.0 * (rz_acc[0] / (double)BSZ) * 0.001);
  }
}

extern "C" void kernel_launch(void* const* d_in, const int* in_sizes, int n_in,
                              void* d_out, int out_size, void* d_ws, size_t ws_size,
                              hipStream_t stream) {
  const float* x  = (const float*)d_in[0];
  const float* wg = (const float*)d_in[1];
  const float* bg = (const float*)d_in[2];
  const float* W1 = (const float*)d_in[3];
  const float* b1 = (const float*)d_in[4];
  const float* W2 = (const float*)d_in[5];
  const float* b2 = (const float*)d_in[6];
  const float* W3 = (const float*)d_in[7];
  const float* b3 = (const float*)d_in[8];
  float* out = (float*)d_out;

  char* wsb = (char*)d_ws;
  unsigned short* Wf  = (unsigned short*)wsb;            // 327,680 B
  unsigned short* W2A = (unsigned short*)(wsb + 327680); // 8,192 B
  unsigned short* W3A = (unsigned short*)(wsb + 335872); // 8,192 B
  float* acc = (float*)(wsb + 344064);                   // 97 floats

  k_prepw<<<dim3(640), dim3(256), 0, stream>>>(W1, wg, W2, W3, Wf, W2A, W3A, acc);
  k_fused<<<dim3(BSZ / 64), dim3(512), 0, stream>>>(
      x, Wf, b1, bg, wg, W2A, b2, W3A, b3, out, acc, acc + 48, acc + 96);
  k_final<<<dim3(1), dim3(64), 0, stream>>>(acc, acc + 48, acc + 96,
                                            out + (size_t)TT * BSZ * OO);
}

// Round 6
// 217.497 us; speedup vs baseline: 1.2022x; 1.1252x over previous
//
#include <hip/hip_runtime.h>

#define BSZ 32768
#define TT  3
#define OO  16
#define RESCUE_THR 2.5e-3f  // f16 2-pass logit sigma ~2.7e-4; thr ~6.5 sigma of gap err

typedef __attribute__((ext_vector_type(8))) _Float16 f16x8;
typedef __attribute__((ext_vector_type(4))) _Float16 f16x4;
typedef __attribute__((ext_vector_type(4))) float f32x4;

__device__ __forceinline__ unsigned short f2h(float f) {
  return __builtin_bit_cast(unsigned short, (_Float16)f);
}
__device__ __forceinline__ float h2f(unsigned short u) {
  return (float)__builtin_bit_cast(_Float16, u);
}
__device__ __forceinline__ unsigned pack2(unsigned short a, unsigned short b) {
  return (unsigned)a | ((unsigned)b << 16);
}

// Wf: fragment-major f16 table. [nblk=20][itg=16][lane=64][j=8], element =
// W^T[n = nblk*16 + (lane&15)][k = itg*32 + (lane>>4)*8 + j].
// n<256: W1 cols; 256..303: w_gates; 304..319: zero.
// W2A/W3A: A-fragments for the 16x16x16 f16 tail MFMAs, [e][lane][j=0..3]:
//   W2A[m=lane&15][k=(lane>>4)*4+j] = (m<8) ? W2[e][k][m] : 0   (m = h2 unit)
//   W3A[m=lane&15][k=(lane>>4)*4+j] = (k<8) ? W3[e][k][m] : 0   (m = output unit)
__global__ void k_prepw(const float* __restrict__ W1, const float* __restrict__ wg,
                        const float* __restrict__ W2, const float* __restrict__ W3,
                        unsigned short* __restrict__ Wf,
                        unsigned short* __restrict__ W2A,
                        unsigned short* __restrict__ W3A, float* __restrict__ acc) {
  if (blockIdx.x == 0 && threadIdx.x < 97) acc[threadIdx.x] = 0.f;
  for (int idx = blockIdx.x * 256 + threadIdx.x; idx < 20 * 16 * 64 * 8;
       idx += gridDim.x * 256) {
    const int nblk = idx >> 13, itg = (idx >> 9) & 15;
    const int lane = (idx >> 3) & 63, j = idx & 7;
    const int n = nblk * 16 + (lane & 15);
    const int k = itg * 32 + (lane >> 4) * 8 + j;
    float v = 0.f;
    if (n < 256) v = W1[(size_t)(n >> 4) * 8192 + k * 16 + (n & 15)];
    else if (n < 304) v = wg[(size_t)((n - 256) >> 4) * 8192 + k * 16 + ((n - 256) & 15)];
    Wf[idx] = f2h(v);
  }
  const int idx2 = blockIdx.x * 256 + threadIdx.x;
  if (idx2 < 16 * 64 * 4) {
    const int e = idx2 >> 8, lane = (idx2 >> 2) & 63, j = idx2 & 3;
    const int m = lane & 15, k = (lane >> 4) * 4 + j;
    W2A[idx2] = f2h((m < 8) ? W2[e * 128 + k * 8 + m] : 0.f);
    W3A[idx2] = f2h((k < 8) ? W3[e * 128 + k * 16 + m] : 0.f);
  }
}

struct FSmem {
  union {
    struct {                            // phase a: x chunk (BK=128), frag order
      unsigned short xh[4][4][64][8];   // [m][it][lane][8] — 16 KB (f16 hi)
      unsigned short xl[4][4][64][8];   // 16 KB (f16 lo)
    } a;
    struct {                            // phase b (53.5 KB)
      float lgs[64][52];                // logits; dead after gating
      unsigned short eoL[64][16][16];   // f16 eo, [row][e][o^swz] — 32 KB
      float gvL[64][12];
      int   giL[64][12];
      float impL[48], loadL[48];
      int   nresc, resc[192];
      double resL[16];
    } b;
  } u;
  float rzrow[64];
};

// launch_bounds(512, 2): ≤128-VGPR budget with 2 blocks/CU residency under
// either (waves/EU | blocks/CU) semantics. (512,4) pinned the allocator at
// 64 VGPRs -> ~290 MB/dispatch scratch spill traffic (rounds 2-5).
__global__ __launch_bounds__(512, 2) void k_fused(
    const float* __restrict__ x, const unsigned short* __restrict__ Wf,
    const float* __restrict__ b1, const float* __restrict__ bg,
    const float* __restrict__ wg, const unsigned short* __restrict__ W2A,
    const float* __restrict__ b2, const unsigned short* __restrict__ W3A,
    const float* __restrict__ b3, float* __restrict__ out, float* acc_imp,
    float* acc_load, float* rz_acc) {
  __shared__ FSmem sm;
  const int tid = threadIdx.x;
  const int b0 = blockIdx.x * 64;
  const int w = tid >> 6, l = tid & 63;
  const int l15 = l & 15, quad = l >> 4;
  const int mh = w >> 2;   // batch-col half (0: rows 0-31, 1: rows 32-63)
  const int cg = w & 3;    // n-col group (80 n each)
  const int srow = tid >> 3, skf = tid & 7;          // staging: row, float4-slot
  const int sm_abs = srow >> 4;
  const int slane = (srow & 15) + 16 * (skf >> 1);
  const int sj = (skf & 1) * 4;

  // acc holds h1^T fragments: row = n_local (quad*4+reg), col = batch (l15).
  f32x4 acc[2][5];
#pragma unroll
  for (int m = 0; m < 2; m++)
#pragma unroll
    for (int c = 0; c < 5; c++) acc[m][c] = (f32x4){0.f, 0.f, 0.f, 0.f};
  float rzsum = 0.f;

  auto woffs = [&](int itg, int c) -> size_t {
    return ((size_t)(((cg * 5 + c) * 16 + itg) * 64 + l)) * 8;
  };

  const float* xbase = &x[(size_t)(b0 + srow) * 512 + skf * 4];
  float4 xv[4];
#pragma unroll
  for (int r = 0; r < 4; r++) xv[r] = *(const float4*)(xbase + r * 32);

#pragma unroll 1
  for (int ch = 0; ch < 4; ++ch) {
    if (ch) __syncthreads();  // protect chunk overwrite
    {
#pragma unroll
      for (int r = 0; r < 4; r++) {
        const float v0 = xv[r].x, v1 = xv[r].y, v2 = xv[r].z, v3 = xv[r].w;
        rzsum += __expf(v0) + __expf(v1) + __expf(v2) + __expf(v3);
        const unsigned short h0 = f2h(v0), h1_ = f2h(v1), h2_ = f2h(v2), h3 = f2h(v3);
        uint2 ph, pl;
        ph.x = pack2(h0, h1_); ph.y = pack2(h2_, h3);
        pl.x = pack2(f2h(v0 - h2f(h0)), f2h(v1 - h2f(h1_)));
        pl.y = pack2(f2h(v2 - h2f(h2_)), f2h(v3 - h2f(h3)));
        *(uint2*)&sm.u.a.xh[sm_abs][r][slane][sj] = ph;
        *(uint2*)&sm.u.a.xl[sm_abs][r][slane][sj] = pl;
      }
    }
    __syncthreads();

    // W fragment stream, depth-2 rolling prefetch
    f16x8 bh0 = *(const f16x8*)&Wf[woffs(ch * 4, 0)];
    f16x8 bh1 = *(const f16x8*)&Wf[woffs(ch * 4, 1)];
    // T14: issue next chunk's x loads now; consumed after this GEMM phase
    if (ch < 3) {
#pragma unroll
      for (int r = 0; r < 4; r++)
        xv[r] = *(const float4*)(xbase + (ch + 1) * 128 + r * 32);
    }
    f16x8 ah[2], al[2];
#pragma unroll
    for (int i = 0; i < 20; ++i) {
      const int it = i / 5, c = i % 5;
      if (c == 0) {
#pragma unroll
        for (int m = 0; m < 2; m++) {
          ah[m] = *(const f16x8*)&sm.u.a.xh[mh * 2 + m][it][l][0];
          al[m] = *(const f16x8*)&sm.u.a.xl[mh * 2 + m][it][l][0];
        }
      }
      f16x8 bh2 = bh0;
      if (i + 2 < 20) bh2 = *(const f16x8*)&Wf[woffs(ch * 4 + (i + 2) / 5, (i + 2) % 5)];
      // A = W fragment, B = x fragment  ->  D = h1^T (row=n, col=batch)
#pragma unroll
      for (int m = 0; m < 2; m++) {
        acc[m][c] = __builtin_amdgcn_mfma_f32_16x16x32_f16(bh0, ah[m], acc[m][c], 0, 0, 0);
        acc[m][c] = __builtin_amdgcn_mfma_f32_16x16x32_f16(bh0, al[m], acc[m][c], 0, 0, 0);
      }
      bh0 = bh1; bh1 = bh2;
    }
  }

  // ---- router-z: 8 threads share a row ----
  rzsum += __shfl_xor(rzsum, 1);
  rzsum += __shfl_xor(rzsum, 2);
  rzsum += __shfl_xor(rzsum, 4);
  if (skf == 0) sm.rzrow[srow] = rzsum;
  __syncthreads();  // GEMM LDS reads done: phase-b region writes safe

  if (tid < 64) {
    float vv = __logf(sm.rzrow[tid]);
#pragma unroll
    for (int off = 32; off; off >>= 1) vv += __shfl_xor(vv, off);
    if (tid == 0) atomicAdd(rz_acc, vv);
  }
  // logits -> lgs (cg 3 holds n 240..319; c=1..3 are the 48 gate cols)
  if (cg == 3) {
#pragma unroll
    for (int c = 1; c < 4; c++) {
#pragma unroll
      for (int m = 0; m < 2; m++)
#pragma unroll
        for (int reg = 0; reg < 4; reg++) {
          const int row = 32 * mh + 16 * m + l15;
          const int cc = 16 * (c - 1) + quad * 4 + reg;
          sm.u.b.lgs[row][cc] = acc[m][c][reg] + bg[cc];
        }
    }
  }

  // ---- MFMA expert tail NOW (before gating): acc dies here ----
  // acc[m][c] (bias+relu, f16) is directly the B-operand (col=batch l15,
  // k=n_local=quad*4+reg) of 16x16x16 f16 MFMAs with W2A/W3A as A.
  {
    const int nexp = (cg < 3) ? 5 : 1;  // cg==3 owns only expert 15 (c=0)
#pragma unroll
    for (int m = 0; m < 2; ++m) {
#pragma unroll
      for (int c = 0; c < 5; ++c) {
        if (c < nexp) {
          const int e = 5 * cg + c;
          const f32x4 b1v = *(const f32x4*)&b1[(e << 4) + quad * 4];
          f16x4 h1f;
#pragma unroll
          for (int r = 0; r < 4; r++)
            h1f[r] = (_Float16)fmaxf(acc[m][c][r] + b1v[r], 0.f);
          const f16x4 w2 = *(const f16x4*)&W2A[((size_t)e * 64 + l) * 4];
          f32x4 h2 = (quad < 2) ? *(const f32x4*)&b2[e * 8 + quad * 4]
                                : (f32x4){0.f, 0.f, 0.f, 0.f};
          h2 = __builtin_amdgcn_mfma_f32_16x16x16f16(w2, h1f, h2, 0, 0, 0);
          f16x4 h2q;
#pragma unroll
          for (int r = 0; r < 4; r++) h2q[r] = (_Float16)fmaxf(h2[r], 0.f);
          const f16x4 w3 = *(const f16x4*)&W3A[((size_t)e * 64 + l) * 4];
          f32x4 eo = *(const f32x4*)&b3[(e << 4) + quad * 4];
          eo = __builtin_amdgcn_mfma_f32_16x16x16f16(w3, h2q, eo, 0, 0, 0);
          // eo^T frag: row=o=quad*4+r, col=batch=l15. Pack f16, XOR-swizzle
          // the o-slot by (l15&3) to spread combine-read banks.
          f16x4 eoh;
#pragma unroll
          for (int r = 0; r < 4; r++) eoh[r] = (_Float16)fmaxf(eo[r], 0.f);
          const int row = mh * 32 + m * 16 + l15;
          *(f16x4*)&sm.u.b.eoL[row][e][(quad * 4) ^ ((l15 & 3) << 2)] = eoh;
        }
      }
    }
  }
  if (tid < 48) { sm.u.b.impL[tid] = 0.f; sm.u.b.loadL[tid] = 0.f; }
  if (tid == 0) sm.u.b.nresc = 0;
  __syncthreads();

  // ---- gating: 192 threads = 3 tasks x 64 rows (masked top-k) ----
  if (tid < 192) {
    const int r = tid & 63, tk = tid >> 6;
    float v[16];
#pragma unroll
    for (int e = 0; e < 16; e++) v[e] = sm.u.b.lgs[r][tk * 16 + e];
    unsigned used = 0;
    int idx[5]; float val[5];
#pragma unroll
    for (int p = 0; p < 5; p++) {
      float best = -INFINITY; int bi = 0;
#pragma unroll
      for (int e = 0; e < 16; e++) {
        const float ve = ((used >> e) & 1u) ? -INFINITY : v[e];
        if (ve > best) { best = ve; bi = e; }
      }
      idx[p] = bi; val[p] = best; used |= 1u << bi;
    }
    if (val[3] - val[4] < RESCUE_THR) {
      const int s = atomicAdd(&sm.u.b.nresc, 1);
      sm.u.b.resc[s] = (r << 2) | tk;
    }
    const float m = val[0];
    float ex[4], sum = 0.f;
#pragma unroll
    for (int p = 0; p < 4; p++) { ex[p] = __expf(val[p] - m); sum += ex[p]; }
#pragma unroll
    for (int p = 0; p < 4; p++) {
      const float g = ex[p] / sum;
      sm.u.b.gvL[r][tk * 4 + p] = g;
      sm.u.b.giL[r][tk * 4 + p] = idx[p];
      atomicAdd(&sm.u.b.impL[tk * 16 + idx[p]], g);
      atomicAdd(&sm.u.b.loadL[tk * 16 + idx[p]], 1.f);
    }
  }
  __syncthreads();

  // ---- cooperative f64 rescue for near-ties ----
  const int nr = sm.u.b.nresc;
  for (int i = 0; i < nr; i++) {
    const int st = sm.u.b.resc[i];
    const int r = st >> 2, tk = st & 3;
    if (tid < 256) {
      const int e = tid >> 4, part = tid & 15;
      const float* xr2 = &x[(size_t)(b0 + r) * 512];
      const float* wgc = &wg[(size_t)tk * 8192 + e];
      double a = 0.0;
      for (int d = part * 32; d < part * 32 + 32; d++)
        a += (double)xr2[d] * (double)wgc[(size_t)d * 16];
#pragma unroll
      for (int off = 1; off < 16; off <<= 1) a += __shfl_xor(a, off);
      if (part == 0) sm.u.b.resL[e] = a + (double)bg[tk * 16 + e];
    }
    __syncthreads();
    if (tid == 0) {
      for (int p = 0; p < 4; p++) {
        sm.u.b.impL[tk * 16 + sm.u.b.giL[r][tk * 4 + p]] -= sm.u.b.gvL[r][tk * 4 + p];
        sm.u.b.loadL[tk * 16 + sm.u.b.giL[r][tk * 4 + p]] -= 1.f;
      }
      unsigned used = 0;
      int idx[4]; float val[4];
      for (int p = 0; p < 4; p++) {
        double best = -1e300; int bi = 0;
        for (int e2 = 0; e2 < 16; e2++) {
          if ((used >> e2) & 1u) continue;
          const double ve = sm.u.b.resL[e2];
          if (ve > best) { best = ve; bi = e2; }
        }
        idx[p] = bi; val[p] = (float)best; used |= 1u << bi;
      }
      const float m = val[0];
      float ex[4], sum = 0.f;
      for (int p = 0; p < 4; p++) { ex[p] = __expf(val[p] - m); sum += ex[p]; }
      for (int p = 0; p < 4; p++) {
        const float g = ex[p] / sum;
        sm.u.b.gvL[r][tk * 4 + p] = g;
        sm.u.b.giL[r][tk * 4 + p] = idx[p];
        sm.u.b.impL[tk * 16 + idx[p]] += g;
        sm.u.b.loadL[tk * 16 + idx[p]] += 1.f;
      }
    }
    __syncthreads();
  }
  if (tid < 48) {
    atomicAdd(&acc_imp[tid], sm.u.b.impL[tid]);
    atomicAdd(&acc_load[tid], sm.u.b.loadL[tid]);
  }

  // ---- combine: 2 barrier-free passes of 32 rows x 16 outputs ----
#pragma unroll
  for (int p2 = 0; p2 < 2; ++p2) {
    const int rl = p2 * 32 + (tid >> 4), o = tid & 15;
    const int osw = (rl & 3) << 2;
#pragma unroll
    for (int tk = 0; tk < TT; tk++) {
      float y = 0.f;
#pragma unroll
      for (int p = 0; p < 4; p++)
        y += sm.u.b.gvL[rl][tk * 4 + p] *
             h2f(sm.u.b.eoL[rl][sm.u.b.giL[rl][tk * 4 + p]][o ^ osw]);
      out[((size_t)tk * BSZ + b0 + rl) * OO + o] = y;
    }
  }
}

__global__ void k_final(const float* __restrict__ acc_imp,
                        const float* __restrict__ acc_load,
                        const float* __restrict__ rz_acc,
                        float* __restrict__ out_tail) {
  if (threadIdx.x == 0 && blockIdx.x == 0) {
    double lb = 0.0;
    for (int t = 0; t < TT; t++) {
      const float* imp = &acc_imp[t * 16];
      const float* ld = &acc_load[t * 16];
      double si = 0, sl = 0, dot = 0;
      for (int e2 = 0; e2 < 16; e2++) {
        si += imp[e2]; sl += ld[e2]; dot += (double)imp[e2] * ld[e2];
      }
      const double mi = si / 16.0, ml = sl / 16.0;
      double vi = 0, vl = 0;
      for (int e2 = 0; e2 < 16; e2++) {
        const double di = imp[e2] - mi, dl = ld[e2] - ml;
        vi += di * di; vl += dl * dl;
      }
      vi /= 15.0; vl /= 15.0;
      lb += (vi / (mi * mi + 1e-10) + vl / (ml * ml + 1e-10)) * 0.01
          + 16.0 * dot / (double)BSZ * 0.01;
    }
    out_tail[0] = (float)lb;
    out_tail[1] = (float)(3.0 * (rz_acc[0] / (double)BSZ) * 0.001);
  }
}

extern "C" void kernel_launch(void* const* d_in, const int* in_sizes, int n_in,
                              void* d_out, int out_size, void* d_ws, size_t ws_size,
                              hipStream_t stream) {
  const float* x  = (const float*)d_in[0];
  const float* wg = (const float*)d_in[1];
  const float* bg = (const float*)d_in[2];
  const float* W1 = (const float*)d_in[3];
  const float* b1 = (const float*)d_in[4];
  const float* W2 = (const float*)d_in[5];
  const float* b2 = (const float*)d_in[6];
  const float* W3 = (const float*)d_in[7];
  const float* b3 = (const float*)d_in[8];
  float* out = (float*)d_out;

  char* wsb = (char*)d_ws;
  unsigned short* Wf  = (unsigned short*)wsb;            // 327,680 B
  unsigned short* W2A = (unsigned short*)(wsb + 327680); // 8,192 B
  unsigned short* W3A = (unsigned short*)(wsb + 335872); // 8,192 B
  float* acc = (float*)(wsb + 344064);                   // 97 floats

  k_prepw<<<dim3(640), dim3(256), 0, stream>>>(W1, wg, W2, W3, Wf, W2A, W3A, acc);
  k_fused<<<dim3(BSZ / 64), dim3(512), 0, stream>>>(
      x, Wf, b1, bg, wg, W2A, b2, W3A, b3, out, acc, acc + 48, acc + 96);
  k_final<<<dim3(1), dim3(64), 0, stream>>>(acc, acc + 48, acc + 96,
                                            out + (size_t)TT * BSZ * OO);
}

// Round 7
// 211.970 us; speedup vs baseline: 1.2336x; 1.0261x over previous
//
#include <hip/hip_runtime.h>

#define BSZ 32768
#define TT  3
#define OO  16
#define RESCUE_THR 2.5e-3f  // f16 2-pass logit sigma ~2.7e-4; thr ~6.5 sigma of gap err

typedef __attribute__((ext_vector_type(8))) _Float16 f16x8;
typedef __attribute__((ext_vector_type(4))) _Float16 f16x4;
typedef __attribute__((ext_vector_type(4))) float f32x4;

__device__ __forceinline__ unsigned short f2h(float f) {
  return __builtin_bit_cast(unsigned short, (_Float16)f);
}
__device__ __forceinline__ float h2f(unsigned short u) {
  return (float)__builtin_bit_cast(_Float16, u);
}
__device__ __forceinline__ unsigned pack2(unsigned short a, unsigned short b) {
  return (unsigned)a | ((unsigned)b << 16);
}

// Wf: fragment-major f16 table. [nblk=20][itg=16][lane=64][j=8], element =
// W^T[n = nblk*16 + (lane&15)][k = itg*32 + (lane>>4)*8 + j].
// n<256: W1 cols; 256..303: w_gates; 304..319: zero.
// W2A/W3A: A-fragments for the 16x16x16 f16 tail MFMAs, [e][lane][j=0..3]:
//   W2A[m=lane&15][k=(lane>>4)*4+j] = (m<8) ? W2[e][k][m] : 0   (m = h2 unit)
//   W3A[m=lane&15][k=(lane>>4)*4+j] = (k<8) ? W3[e][k][m] : 0   (m = output unit)
__global__ void k_prepw(const float* __restrict__ W1, const float* __restrict__ wg,
                        const float* __restrict__ W2, const float* __restrict__ W3,
                        unsigned short* __restrict__ Wf,
                        unsigned short* __restrict__ W2A,
                        unsigned short* __restrict__ W3A, float* __restrict__ acc) {
  if (blockIdx.x == 0 && threadIdx.x < 97) acc[threadIdx.x] = 0.f;
  for (int idx = blockIdx.x * 256 + threadIdx.x; idx < 20 * 16 * 64 * 8;
       idx += gridDim.x * 256) {
    const int nblk = idx >> 13, itg = (idx >> 9) & 15;
    const int lane = (idx >> 3) & 63, j = idx & 7;
    const int n = nblk * 16 + (lane & 15);
    const int k = itg * 32 + (lane >> 4) * 8 + j;
    float v = 0.f;
    if (n < 256) v = W1[(size_t)(n >> 4) * 8192 + k * 16 + (n & 15)];
    else if (n < 304) v = wg[(size_t)((n - 256) >> 4) * 8192 + k * 16 + ((n - 256) & 15)];
    Wf[idx] = f2h(v);
  }
  const int idx2 = blockIdx.x * 256 + threadIdx.x;
  if (idx2 < 16 * 64 * 4) {
    const int e = idx2 >> 8, lane = (idx2 >> 2) & 63, j = idx2 & 3;
    const int m = lane & 15, k = (lane >> 4) * 4 + j;
    W2A[idx2] = f2h((m < 8) ? W2[e * 128 + k * 8 + m] : 0.f);
    W3A[idx2] = f2h((k < 8) ? W3[e * 128 + k * 16 + m] : 0.f);
  }
}

// 32-row blocks, 256 threads (4 waves = 4 col-groups), BK=256 (2 chunks).
// LDS 32.8 KB; grid 1024 -> 4 blocks/CU co-resident (4 independent barrier
// groups vs round-6's 2; per-block serial chain halved; same 16 waves/CU).
struct FSmem {
  union {
    struct {                            // phase a: x chunk (BK=256), frag order
      unsigned short xh[2][8][64][8];   // [m][it][lane][8] — 16 KB (f16 hi)
      unsigned short xl[2][8][64][8];   // 16 KB (f16 lo)
    } a;
    struct {                            // phase b (~27 KB)
      float lgs[32][52];                // logits; dead after gating
      unsigned short eoL[32][16][16];   // f16 eo, [row][e][o^swz] — 16 KB
      float gvL[32][12];
      int   giL[32][12];
      float impL[48], loadL[48];
      int   nresc, resc[96];
      double resL[16];
      float rzrow[32];
    } b;
  } u;
};

__global__ __launch_bounds__(256, 4) void k_fused(
    const float* __restrict__ x, const unsigned short* __restrict__ Wf,
    const float* __restrict__ b1, const float* __restrict__ bg,
    const float* __restrict__ wg, const unsigned short* __restrict__ W2A,
    const float* __restrict__ b2, const unsigned short* __restrict__ W3A,
    const float* __restrict__ b3, float* __restrict__ out, float* acc_imp,
    float* acc_load, float* rz_acc) {
  __shared__ FSmem sm;
  const int tid = threadIdx.x;
  const int b0 = blockIdx.x * 32;
  const int w = tid >> 6, l = tid & 63;
  const int l15 = l & 15, quad = l >> 4;
  const int cg = w;        // n-col group (80 n each), 4 waves
  const int srow = tid >> 3, skf = tid & 7;          // staging: row, float4-slot
  const int sm_abs = srow >> 4;
  const int slane = (srow & 15) + 16 * (skf >> 1);
  const int sj = (skf & 1) * 4;

  // acc holds h1^T fragments: row = n_local (quad*4+reg), col = batch (l15).
  f32x4 acc[2][5];
#pragma unroll
  for (int m = 0; m < 2; m++)
#pragma unroll
    for (int c = 0; c < 5; c++) acc[m][c] = (f32x4){0.f, 0.f, 0.f, 0.f};
  float rzsum = 0.f;

  auto woffs = [&](int itg, int c) -> size_t {
    return ((size_t)(((cg * 5 + c) * 16 + itg) * 64 + l)) * 8;
  };

  const float* xbase = &x[(size_t)(b0 + srow) * 512 + skf * 4];
  float4 xv[8];
#pragma unroll
  for (int r = 0; r < 8; r++) xv[r] = *(const float4*)(xbase + r * 32);
  float4 xp[4];  // chunk-1 partial prefetch (only 4 float4 live across GEMM)

#pragma unroll 1
  for (int ch = 0; ch < 2; ++ch) {
    if (ch) {
      __syncthreads();  // protect chunk overwrite
#pragma unroll
      for (int r = 0; r < 4; r++) xv[r] = xp[r];
#pragma unroll
      for (int r = 4; r < 8; r++)
        xv[r] = *(const float4*)(xbase + 256 + r * 32);
    }
    {
#pragma unroll
      for (int r = 0; r < 8; r++) {
        const float v0 = xv[r].x, v1 = xv[r].y, v2 = xv[r].z, v3 = xv[r].w;
        rzsum += __expf(v0) + __expf(v1) + __expf(v2) + __expf(v3);
        const unsigned short h0 = f2h(v0), h1_ = f2h(v1), h2_ = f2h(v2), h3 = f2h(v3);
        uint2 ph, pl;
        ph.x = pack2(h0, h1_); ph.y = pack2(h2_, h3);
        pl.x = pack2(f2h(v0 - h2f(h0)), f2h(v1 - h2f(h1_)));
        pl.y = pack2(f2h(v2 - h2f(h2_)), f2h(v3 - h2f(h3)));
        *(uint2*)&sm.u.a.xh[sm_abs][r][slane][sj] = ph;
        *(uint2*)&sm.u.a.xl[sm_abs][r][slane][sj] = pl;
      }
    }
    __syncthreads();

    // W fragment stream, depth-2 rolling prefetch
    f16x8 bh0 = *(const f16x8*)&Wf[woffs(ch * 8, 0)];
    f16x8 bh1 = *(const f16x8*)&Wf[woffs(ch * 8, 1)];
    // T14: issue part of next chunk's x loads now (4 float4 = 16 VGPR)
    if (ch == 0) {
#pragma unroll
      for (int r = 0; r < 4; r++)
        xp[r] = *(const float4*)(xbase + 256 + r * 32);
    }
    f16x8 ah[2], al[2];
#pragma unroll
    for (int i = 0; i < 40; ++i) {
      const int it = i / 5, c = i % 5;
      if (c == 0) {
#pragma unroll
        for (int m = 0; m < 2; m++) {
          ah[m] = *(const f16x8*)&sm.u.a.xh[m][it][l][0];
          al[m] = *(const f16x8*)&sm.u.a.xl[m][it][l][0];
        }
      }
      f16x8 bh2 = bh0;
      if (i + 2 < 40) bh2 = *(const f16x8*)&Wf[woffs(ch * 8 + (i + 2) / 5, (i + 2) % 5)];
      // A = W fragment, B = x fragment  ->  D = h1^T (row=n, col=batch)
      // cg==3,c==4 is the all-zero pad (n 304..319): skip the MFMAs.
      if (!(c == 4 && cg == 3)) {
#pragma unroll
        for (int m = 0; m < 2; m++) {
          acc[m][c] = __builtin_amdgcn_mfma_f32_16x16x32_f16(bh0, ah[m], acc[m][c], 0, 0, 0);
          acc[m][c] = __builtin_amdgcn_mfma_f32_16x16x32_f16(bh0, al[m], acc[m][c], 0, 0, 0);
        }
      }
      bh0 = bh1; bh1 = bh2;
    }
  }

  // ---- router-z partial: 8 threads share a row ----
  rzsum += __shfl_xor(rzsum, 1);
  rzsum += __shfl_xor(rzsum, 2);
  rzsum += __shfl_xor(rzsum, 4);

  __syncthreads();  // GEMM LDS reads done: phase-b region writes safe

  if (skf == 0) sm.u.b.rzrow[srow] = rzsum;
  // logits -> lgs (cg 3 holds n 240..319; c=1..3 are the 48 gate cols)
  if (cg == 3) {
#pragma unroll
    for (int c = 1; c < 4; c++) {
#pragma unroll
      for (int m = 0; m < 2; m++)
#pragma unroll
        for (int reg = 0; reg < 4; reg++) {
          const int row = 16 * m + l15;
          const int cc = 16 * (c - 1) + quad * 4 + reg;
          sm.u.b.lgs[row][cc] = acc[m][c][reg] + bg[cc];
        }
    }
  }

  // ---- MFMA expert tail (before gating): acc dies here ----
  // acc[m][c] (bias+relu, f16) is directly the B-operand (col=batch l15,
  // k=n_local=quad*4+reg) of 16x16x16 f16 MFMAs with W2A/W3A as A.
  {
    const int nexp = (cg < 3) ? 5 : 1;  // cg==3 owns only expert 15 (c=0)
#pragma unroll
    for (int m = 0; m < 2; ++m) {
#pragma unroll
      for (int c = 0; c < 5; ++c) {
        if (c < nexp) {
          const int e = 5 * cg + c;
          const f32x4 b1v = *(const f32x4*)&b1[(e << 4) + quad * 4];
          f16x4 h1f;
#pragma unroll
          for (int r = 0; r < 4; r++)
            h1f[r] = (_Float16)fmaxf(acc[m][c][r] + b1v[r], 0.f);
          const f16x4 w2 = *(const f16x4*)&W2A[((size_t)e * 64 + l) * 4];
          f32x4 h2 = (quad < 2) ? *(const f32x4*)&b2[e * 8 + quad * 4]
                                : (f32x4){0.f, 0.f, 0.f, 0.f};
          h2 = __builtin_amdgcn_mfma_f32_16x16x16f16(w2, h1f, h2, 0, 0, 0);
          f16x4 h2q;
#pragma unroll
          for (int r = 0; r < 4; r++) h2q[r] = (_Float16)fmaxf(h2[r], 0.f);
          const f16x4 w3 = *(const f16x4*)&W3A[((size_t)e * 64 + l) * 4];
          f32x4 eo = *(const f32x4*)&b3[(e << 4) + quad * 4];
          eo = __builtin_amdgcn_mfma_f32_16x16x16f16(w3, h2q, eo, 0, 0, 0);
          // eo^T frag: row=o=quad*4+r, col=batch=l15. Pack f16, XOR-swizzle
          // the o-slot by (l15&3) to spread combine-read banks.
          f16x4 eoh;
#pragma unroll
          for (int r = 0; r < 4; r++) eoh[r] = (_Float16)fmaxf(eo[r], 0.f);
          const int row = m * 16 + l15;
          *(f16x4*)&sm.u.b.eoL[row][e][(quad * 4) ^ ((l15 & 3) << 2)] = eoh;
        }
      }
    }
  }
  if (tid < 48) { sm.u.b.impL[tid] = 0.f; sm.u.b.loadL[tid] = 0.f; }
  if (tid == 0) sm.u.b.nresc = 0;
  __syncthreads();

  // ---- router-z final reduce (32 rows) ----
  if (tid < 32) {
    float vv = __logf(sm.u.b.rzrow[tid]);
#pragma unroll
    for (int off = 16; off; off >>= 1) vv += __shfl_xor(vv, off);
    if (tid == 0) atomicAdd(rz_acc, vv);
  }

  // ---- gating: 96 threads = 3 tasks x 32 rows (masked top-k) ----
  if (tid < 96) {
    const int r = tid & 31, tk = tid >> 5;
    float v[16];
#pragma unroll
    for (int e = 0; e < 16; e++) v[e] = sm.u.b.lgs[r][tk * 16 + e];
    unsigned used = 0;
    int idx[5]; float val[5];
#pragma unroll
    for (int p = 0; p < 5; p++) {
      float best = -INFINITY; int bi = 0;
#pragma unroll
      for (int e = 0; e < 16; e++) {
        const float ve = ((used >> e) & 1u) ? -INFINITY : v[e];
        if (ve > best) { best = ve; bi = e; }
      }
      idx[p] = bi; val[p] = best; used |= 1u << bi;
    }
    if (val[3] - val[4] < RESCUE_THR) {
      const int s = atomicAdd(&sm.u.b.nresc, 1);
      sm.u.b.resc[s] = (r << 2) | tk;
    }
    const float m = val[0];
    float ex[4], sum = 0.f;
#pragma unroll
    for (int p = 0; p < 4; p++) { ex[p] = __expf(val[p] - m); sum += ex[p]; }
#pragma unroll
    for (int p = 0; p < 4; p++) {
      const float g = ex[p] / sum;
      sm.u.b.gvL[r][tk * 4 + p] = g;
      sm.u.b.giL[r][tk * 4 + p] = idx[p];
      atomicAdd(&sm.u.b.impL[tk * 16 + idx[p]], g);
      atomicAdd(&sm.u.b.loadL[tk * 16 + idx[p]], 1.f);
    }
  }
  __syncthreads();

  // ---- cooperative f64 rescue for near-ties ----
  const int nr = sm.u.b.nresc;
  for (int i = 0; i < nr; i++) {
    const int st = sm.u.b.resc[i];
    const int r = st >> 2, tk = st & 3;
    {
      const int e = tid >> 4, part = tid & 15;
      const float* xr2 = &x[(size_t)(b0 + r) * 512];
      const float* wgc = &wg[(size_t)tk * 8192 + e];
      double a = 0.0;
      for (int d = part * 32; d < part * 32 + 32; d++)
        a += (double)xr2[d] * (double)wgc[(size_t)d * 16];
#pragma unroll
      for (int off = 1; off < 16; off <<= 1) a += __shfl_xor(a, off);
      if (part == 0) sm.u.b.resL[e] = a + (double)bg[tk * 16 + e];
    }
    __syncthreads();
    if (tid == 0) {
      for (int p = 0; p < 4; p++) {
        sm.u.b.impL[tk * 16 + sm.u.b.giL[r][tk * 4 + p]] -= sm.u.b.gvL[r][tk * 4 + p];
        sm.u.b.loadL[tk * 16 + sm.u.b.giL[r][tk * 4 + p]] -= 1.f;
      }
      unsigned used = 0;
      int idx[4]; float val[4];
      for (int p = 0; p < 4; p++) {
        double best = -1e300; int bi = 0;
        for (int e2 = 0; e2 < 16; e2++) {
          if ((used >> e2) & 1u) continue;
          const double ve = sm.u.b.resL[e2];
          if (ve > best) { best = ve; bi = e2; }
        }
        idx[p] = bi; val[p] = (float)best; used |= 1u << bi;
      }
      const float m = val[0];
      float ex[4], sum = 0.f;
      for (int p = 0; p < 4; p++) { ex[p] = __expf(val[p] - m); sum += ex[p]; }
      for (int p = 0; p < 4; p++) {
        const float g = ex[p] / sum;
        sm.u.b.gvL[r][tk * 4 + p] = g;
        sm.u.b.giL[r][tk * 4 + p] = idx[p];
        sm.u.b.impL[tk * 16 + idx[p]] += g;
        sm.u.b.loadL[tk * 16 + idx[p]] += 1.f;
      }
    }
    __syncthreads();
  }
  if (tid < 48) {
    atomicAdd(&acc_imp[tid], sm.u.b.impL[tid]);
    atomicAdd(&acc_load[tid], sm.u.b.loadL[tid]);
  }

  // ---- combine: 2 barrier-free passes of 16 rows x 16 outputs ----
#pragma unroll
  for (int p2 = 0; p2 < 2; ++p2) {
    const int rl = p2 * 16 + (tid >> 4), o = tid & 15;
    const int osw = (rl & 3) << 2;
#pragma unroll
    for (int tk = 0; tk < TT; tk++) {
      float y = 0.f;
#pragma unroll
      for (int p = 0; p < 4; p++)
        y += sm.u.b.gvL[rl][tk * 4 + p] *
             h2f(sm.u.b.eoL[rl][sm.u.b.giL[rl][tk * 4 + p]][o ^ osw]);
      out[((size_t)tk * BSZ + b0 + rl) * OO + o] = y;
    }
  }
}

// Parallel k_final: 48 threads load+shuffle-reduce (the old 1-thread version
// issued ~200 serial dependent global loads).
__global__ void k_final(const float* __restrict__ acc_imp,
                        const float* __restrict__ acc_load,
                        const float* __restrict__ rz_acc,
                        float* __restrict__ out_tail) {
  const int tid = threadIdx.x;           // one wave (64 lanes)
  const int t = tid >> 4, e = tid & 15;  // t=0..2 active, t=3 idle
  const bool act = t < 3;
  const float impf = act ? acc_imp[t * 16 + e] : 0.f;
  const float ldf  = act ? acc_load[t * 16 + e] : 0.f;
  const double imp = impf, ld = ldf;
  double si = imp, sl = ld, dot = imp * ld;
#pragma unroll
  for (int off = 1; off < 16; off <<= 1) {
    si += __shfl_xor(si, off);
    sl += __shfl_xor(sl, off);
    dot += __shfl_xor(dot, off);
  }
  const double mi = si / 16.0, ml = sl / 16.0;
  double vi = (imp - mi) * (imp - mi), vl = (ld - ml) * (ld - ml);
#pragma unroll
  for (int off = 1; off < 16; off <<= 1) {
    vi += __shfl_xor(vi, off);
    vl += __shfl_xor(vl, off);
  }
  const double lb = (vi / 15.0 / (mi * mi + 1e-10) + vl / 15.0 / (ml * ml + 1e-10)) * 0.01
                  + 16.0 * dot / (double)BSZ * 0.01;
  const double l0 = __shfl(lb, 0), l1 = __shfl(lb, 16), l2 = __shfl(lb, 32);
  if (tid == 0) {
    out_tail[0] = (float)(l0 + l1 + l2);
    out_tail[1] = (float)(3.0 * (rz_acc[0] / (double)BSZ) * 0.001);
  }
}

extern "C" void kernel_launch(void* const* d_in, const int* in_sizes, int n_in,
                              void* d_out, int out_size, void* d_ws, size_t ws_size,
                              hipStream_t stream) {
  const float* x  = (const float*)d_in[0];
  const float* wg = (const float*)d_in[1];
  const float* bg = (const float*)d_in[2];
  const float* W1 = (const float*)d_in[3];
  const float* b1 = (const float*)d_in[4];
  const float* W2 = (const float*)d_in[5];
  const float* b2 = (const float*)d_in[6];
  const float* W3 = (const float*)d_in[7];
  const float* b3 = (const float*)d_in[8];
  float* out = (float*)d_out;

  char* wsb = (char*)d_ws;
  unsigned short* Wf  = (unsigned short*)wsb;            // 327,680 B
  unsigned short* W2A = (unsigned short*)(wsb + 327680); // 8,192 B
  unsigned short* W3A = (unsigned short*)(wsb + 335872); // 8,192 B
  float* acc = (float*)(wsb + 344064);                   // 97 floats

  k_prepw<<<dim3(640), dim3(256), 0, stream>>>(W1, wg, W2, W3, Wf, W2A, W3A, acc);
  k_fused<<<dim3(BSZ / 32), dim3(256), 0, stream>>>(
      x, Wf, b1, bg, wg, W2A, b2, W3A, b3, out, acc, acc + 48, acc + 96);
  k_final<<<dim3(1), dim3(64), 0, stream>>>(acc, acc + 48, acc + 96,
                                            out + (size_t)TT * BSZ * OO);
}

// Round 9
// 198.297 us; speedup vs baseline: 1.3187x; 1.0690x over previous
//
#include <hip/hip_runtime.h>

#define BSZ 32768
#define TT  3
#define OO  16
#define RESCUE_THR 2.5e-3f  // f16 2-pass logit sigma ~2.7e-4; thr ~6.5 sigma of gap err

typedef __attribute__((ext_vector_type(8))) _Float16 f16x8;
typedef __attribute__((ext_vector_type(4))) _Float16 f16x4;
typedef __attribute__((ext_vector_type(4))) float f32x4;

__device__ __forceinline__ unsigned short f2h(float f) {
  return __builtin_bit_cast(unsigned short, (_Float16)f);
}
__device__ __forceinline__ float h2f(unsigned short u) {
  return (float)__builtin_bit_cast(_Float16, u);
}
__device__ __forceinline__ unsigned pack2(unsigned short a, unsigned short b) {
  return (unsigned)a | ((unsigned)b << 16);
}

// Wf: fragment-major f16 table. [nblk=20][itg=16][lane=64][j=8], element =
// W^T[n = nblk*16 + (lane&15)][k = itg*32 + (lane>>4)*8 + j].
// n<256: W1 cols; 256..303: w_gates; 304..319: zero.
// W2A/W3A: A-fragments for the 16x16x16 f16 tail MFMAs, [e][lane][j=0..3]:
//   W2A[m=lane&15][k=(lane>>4)*4+j] = (m<8) ? W2[e][k][m] : 0   (m = h2 unit)
//   W3A[m=lane&15][k=(lane>>4)*4+j] = (k<8) ? W3[e][k][m] : 0   (m = output unit)
__global__ void k_prepw(const float* __restrict__ W1, const float* __restrict__ wg,
                        const float* __restrict__ W2, const float* __restrict__ W3,
                        unsigned short* __restrict__ Wf,
                        unsigned short* __restrict__ W2A,
                        unsigned short* __restrict__ W3A, float* __restrict__ acc) {
  if (blockIdx.x == 0 && threadIdx.x < 97) acc[threadIdx.x] = 0.f;
  for (int idx = blockIdx.x * 256 + threadIdx.x; idx < 20 * 16 * 64 * 8;
       idx += gridDim.x * 256) {
    const int nblk = idx >> 13, itg = (idx >> 9) & 15;
    const int lane = (idx >> 3) & 63, j = idx & 7;
    const int n = nblk * 16 + (lane & 15);
    const int k = itg * 32 + (lane >> 4) * 8 + j;
    float v = 0.f;
    if (n < 256) v = W1[(size_t)(n >> 4) * 8192 + k * 16 + (n & 15)];
    else if (n < 304) v = wg[(size_t)((n - 256) >> 4) * 8192 + k * 16 + ((n - 256) & 15)];
    Wf[idx] = f2h(v);
  }
  const int idx2 = blockIdx.x * 256 + threadIdx.x;
  if (idx2 < 16 * 64 * 4) {
    const int e = idx2 >> 8, lane = (idx2 >> 2) & 63, j = idx2 & 3;
    const int m = lane & 15, k = (lane >> 4) * 4 + j;
    W2A[idx2] = f2h((m < 8) ? W2[e * 128 + k * 8 + m] : 0.f);
    W3A[idx2] = f2h((k < 8) ? W3[e * 128 + k * 16 + m] : 0.f);
  }
}

// 32-row blocks, 256 threads (4 waves = 4 col-groups), BK=256 (2 chunks).
// LDS 32.8 KB; grid 1024 -> 4 blocks/CU co-resident (LDS-limited), 16 waves/CU.
struct FSmem {
  union {
    struct {                            // phase a: x chunk (BK=256), frag order
      unsigned short xh[2][8][64][8];   // [m][it][lane][8] — 16 KB (f16 hi)
      unsigned short xl[2][8][64][8];   // 16 KB (f16 lo)
    } a;
    struct {                            // phase b (~27 KB)
      float lgs[32][52];                // logits; dead after gating
      unsigned short eoL[32][16][16];   // f16 eo, [row][e][o^swz] — 16 KB
      float gvL[32][12];
      int   giL[32][12];
      float impL[48], loadL[48];
      int   nresc, resc[96];
      double resL[16];
      float rzrow[32];
    } b;
  } u;
};

// launch_bounds 2nd arg: empirical VGPR cap = 256/arg on gfx950
// (arg 4 -> 64-reg cap -> scratch spill, rounds 2-5,7; arg 2 -> 128 cap).
// Occupancy stays LDS-limited at 4 blocks/CU regardless.
__global__ __launch_bounds__(256, 2) void k_fused(
    const float* __restrict__ x, const unsigned short* __restrict__ Wf,
    const float* __restrict__ b1, const float* __restrict__ bg,
    const float* __restrict__ wg, const unsigned short* __restrict__ W2A,
    const float* __restrict__ b2, const unsigned short* __restrict__ W3A,
    const float* __restrict__ b3, float* __restrict__ out, float* acc_imp,
    float* acc_load, float* rz_acc) {
  __shared__ FSmem sm;
  const int tid = threadIdx.x;
  const int b0 = blockIdx.x * 32;
  const int w = tid >> 6, l = tid & 63;
  const int l15 = l & 15, quad = l >> 4;
  const int cg = w;        // n-col group (80 n each), 4 waves
  const int srow = tid >> 3, skf = tid & 7;          // staging: row, float4-slot
  const int sm_abs = srow >> 4;
  const int slane = (srow & 15) + 16 * (skf >> 1);
  const int sj = (skf & 1) * 4;

  // acc holds h1^T fragments: row = n_local (quad*4+reg), col = batch (l15).
  f32x4 acc[2][5];
#pragma unroll
  for (int m = 0; m < 2; m++)
#pragma unroll
    for (int c = 0; c < 5; c++) acc[m][c] = (f32x4){0.f, 0.f, 0.f, 0.f};
  float rzsum = 0.f;

  auto woffs = [&](int itg, int c) -> size_t {
    return ((size_t)(((cg * 5 + c) * 16 + itg) * 64 + l)) * 8;
  };

  const float* xbase = &x[(size_t)(b0 + srow) * 512 + skf * 4];

#pragma unroll 1
  for (int ch = 0; ch < 2; ++ch) {
    float4 xv[8];
    if (ch) __syncthreads();  // protect chunk overwrite
#pragma unroll
    for (int r = 0; r < 8; r++) xv[r] = *(const float4*)(xbase + ch * 256 + r * 32);
    {
#pragma unroll
      for (int r = 0; r < 8; r++) {
        const float v0 = xv[r].x, v1 = xv[r].y, v2 = xv[r].z, v3 = xv[r].w;
        rzsum += __expf(v0) + __expf(v1) + __expf(v2) + __expf(v3);
        const unsigned short h0 = f2h(v0), h1_ = f2h(v1), h2_ = f2h(v2), h3 = f2h(v3);
        uint2 ph, pl;
        ph.x = pack2(h0, h1_); ph.y = pack2(h2_, h3);
        pl.x = pack2(f2h(v0 - h2f(h0)), f2h(v1 - h2f(h1_)));
        pl.y = pack2(f2h(v2 - h2f(h2_)), f2h(v3 - h2f(h3)));
        *(uint2*)&sm.u.a.xh[sm_abs][r][slane][sj] = ph;
        *(uint2*)&sm.u.a.xl[sm_abs][r][slane][sj] = pl;
      }
    }
    __syncthreads();

    // W fragment stream, depth-2 rolling prefetch
    f16x8 bh0 = *(const f16x8*)&Wf[woffs(ch * 8, 0)];
    f16x8 bh1 = *(const f16x8*)&Wf[woffs(ch * 8, 1)];
    f16x8 ah[2], al[2];
#pragma unroll
    for (int i = 0; i < 40; ++i) {
      const int it = i / 5, c = i % 5;
      if (c == 0) {
#pragma unroll
        for (int m = 0; m < 2; m++) {
          ah[m] = *(const f16x8*)&sm.u.a.xh[m][it][l][0];
          al[m] = *(const f16x8*)&sm.u.a.xl[m][it][l][0];
        }
      }
      f16x8 bh2 = bh0;
      if (i + 2 < 40) bh2 = *(const f16x8*)&Wf[woffs(ch * 8 + (i + 2) / 5, (i + 2) % 5)];
      // A = W fragment, B = x fragment  ->  D = h1^T (row=n, col=batch)
      // cg==3,c==4 is the all-zero pad (n 304..319): skip the MFMAs.
      if (!(c == 4 && cg == 3)) {
#pragma unroll
        for (int m = 0; m < 2; m++) {
          acc[m][c] = __builtin_amdgcn_mfma_f32_16x16x32_f16(bh0, ah[m], acc[m][c], 0, 0, 0);
          acc[m][c] = __builtin_amdgcn_mfma_f32_16x16x32_f16(bh0, al[m], acc[m][c], 0, 0, 0);
        }
      }
      bh0 = bh1; bh1 = bh2;
    }
  }

  // ---- router-z partial: 8 threads share a row ----
  rzsum += __shfl_xor(rzsum, 1);
  rzsum += __shfl_xor(rzsum, 2);
  rzsum += __shfl_xor(rzsum, 4);

  __syncthreads();  // GEMM LDS reads done: phase-b region writes safe

  if (skf == 0) sm.u.b.rzrow[srow] = rzsum;
  // logits -> lgs (cg 3 holds n 240..319; c=1..3 are the 48 gate cols)
  if (cg == 3) {
#pragma unroll
    for (int c = 1; c < 4; c++) {
#pragma unroll
      for (int m = 0; m < 2; m++)
#pragma unroll
        for (int reg = 0; reg < 4; reg++) {
          const int row = 16 * m + l15;
          const int cc = 16 * (c - 1) + quad * 4 + reg;
          sm.u.b.lgs[row][cc] = acc[m][c][reg] + bg[cc];
        }
    }
  }

  // ---- MFMA expert tail (before gating): acc dies here ----
  // acc[m][c] (bias+relu, f16) is directly the B-operand (col=batch l15,
  // k=n_local=quad*4+reg) of 16x16x16 f16 MFMAs with W2A/W3A as A.
  {
    const int nexp = (cg < 3) ? 5 : 1;  // cg==3 owns only expert 15 (c=0)
#pragma unroll
    for (int m = 0; m < 2; ++m) {
#pragma unroll
      for (int c = 0; c < 5; ++c) {
        if (c < nexp) {
          const int e = 5 * cg + c;
          const f32x4 b1v = *(const f32x4*)&b1[(e << 4) + quad * 4];
          f16x4 h1f;
#pragma unroll
          for (int r = 0; r < 4; r++)
            h1f[r] = (_Float16)fmaxf(acc[m][c][r] + b1v[r], 0.f);
          const f16x4 w2 = *(const f16x4*)&W2A[((size_t)e * 64 + l) * 4];
          f32x4 h2 = (quad < 2) ? *(const f32x4*)&b2[e * 8 + quad * 4]
                                : (f32x4){0.f, 0.f, 0.f, 0.f};
          h2 = __builtin_amdgcn_mfma_f32_16x16x16f16(w2, h1f, h2, 0, 0, 0);
          f16x4 h2q;
#pragma unroll
          for (int r = 0; r < 4; r++) h2q[r] = (_Float16)fmaxf(h2[r], 0.f);
          const f16x4 w3 = *(const f16x4*)&W3A[((size_t)e * 64 + l) * 4];
          f32x4 eo = *(const f32x4*)&b3[(e << 4) + quad * 4];
          eo = __builtin_amdgcn_mfma_f32_16x16x16f16(w3, h2q, eo, 0, 0, 0);
          // eo^T frag: row=o=quad*4+r, col=batch=l15. Pack f16, XOR-swizzle
          // the o-slot by (l15&3) to spread combine-read banks.
          f16x4 eoh;
#pragma unroll
          for (int r = 0; r < 4; r++) eoh[r] = (_Float16)fmaxf(eo[r], 0.f);
          const int row = m * 16 + l15;
          *(f16x4*)&sm.u.b.eoL[row][e][(quad * 4) ^ ((l15 & 3) << 2)] = eoh;
        }
      }
    }
  }
  if (tid < 48) { sm.u.b.impL[tid] = 0.f; sm.u.b.loadL[tid] = 0.f; }
  if (tid == 0) sm.u.b.nresc = 0;
  __syncthreads();

  // ---- router-z final reduce (32 rows) ----
  if (tid < 32) {
    float vv = __logf(sm.u.b.rzrow[tid]);
#pragma unroll
    for (int off = 16; off; off >>= 1) vv += __shfl_xor(vv, off);
    if (tid == 0) atomicAdd(rz_acc, vv);
  }

  // ---- gating: 96 threads = 3 tasks x 32 rows (masked top-k) ----
  if (tid < 96) {
    const int r = tid & 31, tk = tid >> 5;
    float v[16];
#pragma unroll
    for (int e = 0; e < 16; e++) v[e] = sm.u.b.lgs[r][tk * 16 + e];
    unsigned used = 0;
    int idx[5]; float val[5];
#pragma unroll
    for (int p = 0; p < 5; p++) {
      float best = -INFINITY; int bi = 0;
#pragma unroll
      for (int e = 0; e < 16; e++) {
        const float ve = ((used >> e) & 1u) ? -INFINITY : v[e];
        if (ve > best) { best = ve; bi = e; }
      }
      idx[p] = bi; val[p] = best; used |= 1u << bi;
    }
    if (val[3] - val[4] < RESCUE_THR) {
      const int s = atomicAdd(&sm.u.b.nresc, 1);
      sm.u.b.resc[s] = (r << 2) | tk;
    }
    const float m = val[0];
    float ex[4], sum = 0.f;
#pragma unroll
    for (int p = 0; p < 4; p++) { ex[p] = __expf(val[p] - m); sum += ex[p]; }
#pragma unroll
    for (int p = 0; p < 4; p++) {
      const float g = ex[p] / sum;
      sm.u.b.gvL[r][tk * 4 + p] = g;
      sm.u.b.giL[r][tk * 4 + p] = idx[p];
      atomicAdd(&sm.u.b.impL[tk * 16 + idx[p]], g);
      atomicAdd(&sm.u.b.loadL[tk * 16 + idx[p]], 1.f);
    }
  }
  __syncthreads();

  // ---- cooperative f64 rescue for near-ties ----
  const int nr = sm.u.b.nresc;
  for (int i = 0; i < nr; i++) {
    const int st = sm.u.b.resc[i];
    const int r = st >> 2, tk = st & 3;
    {
      const int e = tid >> 4, part = tid & 15;
      const float* xr2 = &x[(size_t)(b0 + r) * 512];
      const float* wgc = &wg[(size_t)tk * 8192 + e];
      double a = 0.0;
      for (int d = part * 32; d < part * 32 + 32; d++)
        a += (double)xr2[d] * (double)wgc[(size_t)d * 16];
#pragma unroll
      for (int off = 1; off < 16; off <<= 1) a += __shfl_xor(a, off);
      if (part == 0) sm.u.b.resL[e] = a + (double)bg[tk * 16 + e];
    }
    __syncthreads();
    if (tid == 0) {
      for (int p = 0; p < 4; p++) {
        sm.u.b.impL[tk * 16 + sm.u.b.giL[r][tk * 4 + p]] -= sm.u.b.gvL[r][tk * 4 + p];
        sm.u.b.loadL[tk * 16 + sm.u.b.giL[r][tk * 4 + p]] -= 1.f;
      }
      unsigned used = 0;
      int idx[4]; float val[4];
      for (int p = 0; p < 4; p++) {
        double best = -1e300; int bi = 0;
        for (int e2 = 0; e2 < 16; e2++) {
          if ((used >> e2) & 1u) continue;
          const double ve = sm.u.b.resL[e2];
          if (ve > best) { best = ve; bi = e2; }
        }
        idx[p] = bi; val[p] = (float)best; used |= 1u << bi;
      }
      const float m = val[0];
      float ex[4], sum = 0.f;
      for (int p = 0; p < 4; p++) { ex[p] = __expf(val[p] - m); sum += ex[p]; }
      for (int p = 0; p < 4; p++) {
        const float g = ex[p] / sum;
        sm.u.b.gvL[r][tk * 4 + p] = g;
        sm.u.b.giL[r][tk * 4 + p] = idx[p];
        sm.u.b.impL[tk * 16 + idx[p]] += g;
        sm.u.b.loadL[tk * 16 + idx[p]] += 1.f;
      }
    }
    __syncthreads();
  }
  if (tid < 48) {
    atomicAdd(&acc_imp[tid], sm.u.b.impL[tid]);
    atomicAdd(&acc_load[tid], sm.u.b.loadL[tid]);
  }

  // ---- combine: 2 barrier-free passes of 16 rows x 16 outputs ----
#pragma unroll
  for (int p2 = 0; p2 < 2; ++p2) {
    const int rl = p2 * 16 + (tid >> 4), o = tid & 15;
    const int osw = (rl & 3) << 2;
#pragma unroll
    for (int tk = 0; tk < TT; tk++) {
      float y = 0.f;
#pragma unroll
      for (int p = 0; p < 4; p++)
        y += sm.u.b.gvL[rl][tk * 4 + p] *
             h2f(sm.u.b.eoL[rl][sm.u.b.giL[rl][tk * 4 + p]][o ^ osw]);
      out[((size_t)tk * BSZ + b0 + rl) * OO + o] = y;
    }
  }
}

// Parallel k_final: 48 threads load+shuffle-reduce.
__global__ void k_final(const float* __restrict__ acc_imp,
                        const float* __restrict__ acc_load,
                        const float* __restrict__ rz_acc,
                        float* __restrict__ out_tail) {
  const int tid = threadIdx.x;           // one wave (64 lanes)
  const int t = tid >> 4, e = tid & 15;  // t=0..2 active, t=3 idle
  const bool act = t < 3;
  const float impf = act ? acc_imp[t * 16 + e] : 0.f;
  const float ldf  = act ? acc_load[t * 16 + e] : 0.f;
  const double imp = impf, ld = ldf;
  double si = imp, sl = ld, dot = imp * ld;
#pragma unroll
  for (int off = 1; off < 16; off <<= 1) {
    si += __shfl_xor(si, off);
    sl += __shfl_xor(sl, off);
    dot += __shfl_xor(dot, off);
  }
  const double mi = si / 16.0, ml = sl / 16.0;
  double vi = (imp - mi) * (imp - mi), vl = (ld - ml) * (ld - ml);
#pragma unroll
  for (int off = 1; off < 16; off <<= 1) {
    vi += __shfl_xor(vi, off);
    vl += __shfl_xor(vl, off);
  }
  const double lb = (vi / 15.0 / (mi * mi + 1e-10) + vl / 15.0 / (ml * ml + 1e-10)) * 0.01
                  + 16.0 * dot / (double)BSZ * 0.01;
  const double l0 = __shfl(lb, 0), l1 = __shfl(lb, 16), l2 = __shfl(lb, 32);
  if (tid == 0) {
    out_tail[0] = (float)(l0 + l1 + l2);
    out_tail[1] = (float)(3.0 * (rz_acc[0] / (double)BSZ) * 0.001);
  }
}

extern "C" void kernel_launch(void* const* d_in, const int* in_sizes, int n_in,
                              void* d_out, int out_size, void* d_ws, size_t ws_size,
                              hipStream_t stream) {
  const float* x  = (const float*)d_in[0];
  const float* wg = (const float*)d_in[1];
  const float* bg = (const float*)d_in[2];
  const float* W1 = (const float*)d_in[3];
  const float* b1 = (const float*)d_in[4];
  const float* W2 = (const float*)d_in[5];
  const float* b2 = (const float*)d_in[6];
  const float* W3 = (const float*)d_in[7];
  const float* b3 = (const float*)d_in[8];
  float* out = (float*)d_out;

  char* wsb = (char*)d_ws;
  unsigned short* Wf  = (unsigned short*)wsb;            // 327,680 B
  unsigned short* W2A = (unsigned short*)(wsb + 327680); // 8,192 B
  unsigned short* W3A = (unsigned short*)(wsb + 335872); // 8,192 B
  float* acc = (float*)(wsb + 344064);                   // 97 floats

  k_prepw<<<dim3(640), dim3(256), 0, stream>>>(W1, wg, W2, W3, Wf, W2A, W3A, acc);
  k_fused<<<dim3(BSZ / 32), dim3(256), 0, stream>>>(
      x, Wf, b1, bg, wg, W2A, b2, W3A, b3, out, acc, acc + 48, acc + 96);
  k_final<<<dim3(1), dim3(64), 0, stream>>>(acc, acc + 48, acc + 96,
                                            out + (size_t)TT * BSZ * OO);
}

// Round 12
// 195.880 us; speedup vs baseline: 1.3349x; 1.0123x over previous
//
#include <hip/hip_runtime.h>

#define BSZ 32768
#define TT  3
#define OO  16
#define RESCUE_THR 2.5e-3f  // f16 2-pass logit sigma ~2.7e-4; thr ~6.5 sigma of gap err

typedef __attribute__((ext_vector_type(8))) _Float16 f16x8;
typedef __attribute__((ext_vector_type(4))) _Float16 f16x4;
typedef __attribute__((ext_vector_type(4))) float f32x4;

__device__ __forceinline__ unsigned short f2h(float f) {
  return __builtin_bit_cast(unsigned short, (_Float16)f);
}
__device__ __forceinline__ float h2f(unsigned short u) {
  return (float)__builtin_bit_cast(_Float16, u);
}
__device__ __forceinline__ unsigned pack2(unsigned short a, unsigned short b) {
  return (unsigned)a | ((unsigned)b << 16);
}

// Wf: fragment-major f16 table. [nblk=20][itg=16][lane=64][j=8], element =
// W^T[n = nblk*16 + (lane&15)][k = itg*32 + (lane>>4)*8 + j].
// n<256: W1 cols; 256..303: w_gates; 304..319: zero.
// W2A/W3A: A-fragments for the 16x16x16 f16 tail MFMAs, [e][lane][j=0..3]:
//   W2A[m=lane&15][k=(lane>>4)*4+j] = (m<8) ? W2[e][k][m] : 0   (m = h2 unit)
//   W3A[m=lane&15][k=(lane>>4)*4+j] = (k<8) ? W3[e][k][m] : 0   (m = output unit)
__global__ void k_prepw(const float* __restrict__ W1, const float* __restrict__ wg,
                        const float* __restrict__ W2, const float* __restrict__ W3,
                        unsigned short* __restrict__ Wf,
                        unsigned short* __restrict__ W2A,
                        unsigned short* __restrict__ W3A, float* __restrict__ acc) {
  if (blockIdx.x == 0 && threadIdx.x < 97) acc[threadIdx.x] = 0.f;
  for (int idx = blockIdx.x * 256 + threadIdx.x; idx < 20 * 16 * 64 * 8;
       idx += gridDim.x * 256) {
    const int nblk = idx >> 13, itg = (idx >> 9) & 15;
    const int lane = (idx >> 3) & 63, j = idx & 7;
    const int n = nblk * 16 + (lane & 15);
    const int k = itg * 32 + (lane >> 4) * 8 + j;
    float v = 0.f;
    if (n < 256) v = W1[(size_t)(n >> 4) * 8192 + k * 16 + (n & 15)];
    else if (n < 304) v = wg[(size_t)((n - 256) >> 4) * 8192 + k * 16 + ((n - 256) & 15)];
    Wf[idx] = f2h(v);
  }
  const int idx2 = blockIdx.x * 256 + threadIdx.x;
  if (idx2 < 16 * 64 * 4) {
    const int e = idx2 >> 8, lane = (idx2 >> 2) & 63, j = idx2 & 3;
    const int m = lane & 15, k = (lane >> 4) * 4 + j;
    W2A[idx2] = f2h((m < 8) ? W2[e * 128 + k * 8 + m] : 0.f);
    W3A[idx2] = f2h((k < 8) ? W3[e * 128 + k * 16 + m] : 0.f);
  }
}

// 32-row blocks, 256 threads (4 waves = 4 col-groups), BK=256 (2 chunks).
// LDS 32.8 KB; grid 1024 -> 4 blocks/CU co-resident (LDS-limited), 16 waves/CU.
struct FSmem {
  union {
    struct {                            // phase a: x chunk (BK=256), frag order
      unsigned short xh[2][8][64][8];   // [m][it][lane][8] — 16 KB (f16 hi)
      unsigned short xl[2][8][64][8];   // 16 KB (f16 lo)
    } a;
    struct {                            // phase b (~27 KB)
      float lgs[32][52];                // logits; dead after gating
      unsigned short eoL[32][16][16];   // f16 eo, [row][e][o^swz] — 16 KB
      float gvL[32][12];
      int   giL[32][12];
      float impL[48], loadL[48];
      int   nresc, resc[96];
      double resL[16];
      float rzrow[32];
    } b;
  } u;
};

// launch_bounds 2nd arg: empirical VGPR cap = 256/arg on gfx950
// (arg 4 -> 64-reg cap -> scratch spill; arg 2 -> 128 cap, 84 used, no spill).
// Occupancy stays LDS-limited at 4 blocks/CU regardless.
__global__ __launch_bounds__(256, 2) void k_fused(
    const float* __restrict__ x, const unsigned short* __restrict__ Wf,
    const float* __restrict__ b1, const float* __restrict__ bg,
    const float* __restrict__ wg, const unsigned short* __restrict__ W2A,
    const float* __restrict__ b2, const unsigned short* __restrict__ W3A,
    const float* __restrict__ b3, float* __restrict__ out, float* acc_imp,
    float* acc_load, float* rz_acc) {
  __shared__ FSmem sm;
  const int tid = threadIdx.x;
  const int b0 = blockIdx.x * 32;
  const int w = tid >> 6, l = tid & 63;
  const int l15 = l & 15, quad = l >> 4;
  const int cg = w;        // n-col group (80 n each), 4 waves
  const int srow = tid >> 3, skf = tid & 7;          // staging: row, float4-slot
  const int sm_abs = srow >> 4;
  const int slane = (srow & 15) + 16 * (skf >> 1);
  const int sj = (skf & 1) * 4;

  // acc holds h1^T fragments: row = n_local (quad*4+reg), col = batch (l15).
  f32x4 acc[2][5];
#pragma unroll
  for (int m = 0; m < 2; m++)
#pragma unroll
    for (int c = 0; c < 5; c++) acc[m][c] = (f32x4){0.f, 0.f, 0.f, 0.f};
  float rzsum = 0.f;

  auto woffs = [&](int itg, int c) -> size_t {
    return ((size_t)(((cg * 5 + c) * 16 + itg) * 64 + l)) * 8;
  };

  const float* xbase = &x[(size_t)(b0 + srow) * 512 + skf * 4];

#pragma unroll 1
  for (int ch = 0; ch < 2; ++ch) {
    float4 xv[8];
    if (ch) __syncthreads();  // protect chunk overwrite
#pragma unroll
    for (int r = 0; r < 8; r++) xv[r] = *(const float4*)(xbase + ch * 256 + r * 32);
    {
#pragma unroll
      for (int r = 0; r < 8; r++) {
        const float v0 = xv[r].x, v1 = xv[r].y, v2 = xv[r].z, v3 = xv[r].w;
        rzsum += __expf(v0) + __expf(v1) + __expf(v2) + __expf(v3);
        const unsigned short h0 = f2h(v0), h1_ = f2h(v1), h2_ = f2h(v2), h3 = f2h(v3);
        uint2 ph, pl;
        ph.x = pack2(h0, h1_); ph.y = pack2(h2_, h3);
        pl.x = pack2(f2h(v0 - h2f(h0)), f2h(v1 - h2f(h1_)));
        pl.y = pack2(f2h(v2 - h2f(h2_)), f2h(v3 - h2f(h3)));
        *(uint2*)&sm.u.a.xh[sm_abs][r][slane][sj] = ph;
        *(uint2*)&sm.u.a.xl[sm_abs][r][slane][sj] = pl;
      }
    }
    __syncthreads();

    // Wf stream: depth-6 ring prefetch (L2 lat ~200-400cy; old depth-2 gave
    // ~30cy cover -> per-step vmcnt stall was the top time sink at 8% MfmaUtil).
    // Ring of 8, fully unrolled loop -> all indices static (no scratch).
    f16x8 bh[8];
#pragma unroll
    for (int i = 0; i < 6; ++i)
      bh[i] = *(const f16x8*)&Wf[woffs(ch * 8 + i / 5, i % 5)];
    // x fragments: parity ping-pong, it+1 loads issued at c==1 of group it
    // (~4 MFMA-steps of cover for the ~120cy LDS latency; no reg copies).
    f16x8 ax[2][2], lx[2][2];
#pragma unroll
    for (int m = 0; m < 2; m++) {
      ax[0][m] = *(const f16x8*)&sm.u.a.xh[m][0][l][0];
      lx[0][m] = *(const f16x8*)&sm.u.a.xl[m][0][l][0];
    }
#pragma unroll
    for (int i = 0; i < 40; ++i) {
      const int it = i / 5, c = i % 5, p = it & 1;
      if (c == 1 && it < 7) {
#pragma unroll
        for (int m = 0; m < 2; m++) {
          ax[p ^ 1][m] = *(const f16x8*)&sm.u.a.xh[m][it + 1][l][0];
          lx[p ^ 1][m] = *(const f16x8*)&sm.u.a.xl[m][it + 1][l][0];
        }
      }
      if (i + 6 < 40)
        bh[(i + 6) & 7] = *(const f16x8*)&Wf[woffs(ch * 8 + (i + 6) / 5, (i + 6) % 5)];
      // A = W fragment, B = x fragment  ->  D = h1^T (row=n, col=batch)
      // cg==3,c==4 is the all-zero pad (n 304..319): skip the MFMAs.
      if (!(c == 4 && cg == 3)) {
#pragma unroll
        for (int m = 0; m < 2; m++) {
          acc[m][c] = __builtin_amdgcn_mfma_f32_16x16x32_f16(bh[i & 7], ax[p][m], acc[m][c], 0, 0, 0);
          acc[m][c] = __builtin_amdgcn_mfma_f32_16x16x32_f16(bh[i & 7], lx[p][m], acc[m][c], 0, 0, 0);
        }
      }
    }
  }

  // ---- router-z partial: 8 threads share a row ----
  rzsum += __shfl_xor(rzsum, 1);
  rzsum += __shfl_xor(rzsum, 2);
  rzsum += __shfl_xor(rzsum, 4);

  __syncthreads();  // GEMM LDS reads done: phase-b region writes safe

  if (skf == 0) sm.u.b.rzrow[srow] = rzsum;
  // logits -> lgs (cg 3 holds n 240..319; c=1..3 are the 48 gate cols)
  if (cg == 3) {
#pragma unroll
    for (int c = 1; c < 4; c++) {
#pragma unroll
      for (int m = 0; m < 2; m++)
#pragma unroll
        for (int reg = 0; reg < 4; reg++) {
          const int row = 16 * m + l15;
          const int cc = 16 * (c - 1) + quad * 4 + reg;
          sm.u.b.lgs[row][cc] = acc[m][c][reg] + bg[cc];
        }
    }
  }

  // ---- MFMA expert tail (before gating): acc dies here ----
  // acc[m][c] (bias+relu, f16) is directly the B-operand (col=batch l15,
  // k=n_local=quad*4+reg) of 16x16x16 f16 MFMAs with W2A/W3A as A.
  {
    const int nexp = (cg < 3) ? 5 : 1;  // cg==3 owns only expert 15 (c=0)
#pragma unroll
    for (int m = 0; m < 2; ++m) {
#pragma unroll
      for (int c = 0; c < 5; ++c) {
        if (c < nexp) {
          const int e = 5 * cg + c;
          const f32x4 b1v = *(const f32x4*)&b1[(e << 4) + quad * 4];
          f16x4 h1f;
#pragma unroll
          for (int r = 0; r < 4; r++)
            h1f[r] = (_Float16)fmaxf(acc[m][c][r] + b1v[r], 0.f);
          const f16x4 w2 = *(const f16x4*)&W2A[((size_t)e * 64 + l) * 4];
          f32x4 h2 = (quad < 2) ? *(const f32x4*)&b2[e * 8 + quad * 4]
                                : (f32x4){0.f, 0.f, 0.f, 0.f};
          h2 = __builtin_amdgcn_mfma_f32_16x16x16f16(w2, h1f, h2, 0, 0, 0);
          f16x4 h2q;
#pragma unroll
          for (int r = 0; r < 4; r++) h2q[r] = (_Float16)fmaxf(h2[r], 0.f);
          const f16x4 w3 = *(const f16x4*)&W3A[((size_t)e * 64 + l) * 4];
          f32x4 eo = *(const f32x4*)&b3[(e << 4) + quad * 4];
          eo = __builtin_amdgcn_mfma_f32_16x16x16f16(w3, h2q, eo, 0, 0, 0);
          // eo^T frag: row=o=quad*4+r, col=batch=l15. Pack f16, XOR-swizzle
          // the o-slot by (l15&3) to spread combine-read banks.
          f16x4 eoh;
#pragma unroll
          for (int r = 0; r < 4; r++) eoh[r] = (_Float16)fmaxf(eo[r], 0.f);
          const int row = m * 16 + l15;
          *(f16x4*)&sm.u.b.eoL[row][e][(quad * 4) ^ ((l15 & 3) << 2)] = eoh;
        }
      }
    }
  }
  if (tid < 48) { sm.u.b.impL[tid] = 0.f; sm.u.b.loadL[tid] = 0.f; }
  if (tid == 0) sm.u.b.nresc = 0;
  __syncthreads();

  // ---- router-z final reduce (32 rows) ----
  if (tid < 32) {
    float vv = __logf(sm.u.b.rzrow[tid]);
#pragma unroll
    for (int off = 16; off; off >>= 1) vv += __shfl_xor(vv, off);
    if (tid == 0) atomicAdd(rz_acc, vv);
  }

  // ---- gating: 96 threads = 3 tasks x 32 rows (masked top-k) ----
  if (tid < 96) {
    const int r = tid & 31, tk = tid >> 5;
    float v[16];
#pragma unroll
    for (int e = 0; e < 16; e++) v[e] = sm.u.b.lgs[r][tk * 16 + e];
    unsigned used = 0;
    int idx[5]; float val[5];
#pragma unroll
    for (int p = 0; p < 5; p++) {
      float best = -INFINITY; int bi = 0;
#pragma unroll
      for (int e = 0; e < 16; e++) {
        const float ve = ((used >> e) & 1u) ? -INFINITY : v[e];
        if (ve > best) { best = ve; bi = e; }
      }
      idx[p] = bi; val[p] = best; used |= 1u << bi;
    }
    if (val[3] - val[4] < RESCUE_THR) {
      const int s = atomicAdd(&sm.u.b.nresc, 1);
      sm.u.b.resc[s] = (r << 2) | tk;
    }
    const float m = val[0];
    float ex[4], sum = 0.f;
#pragma unroll
    for (int p = 0; p < 4; p++) { ex[p] = __expf(val[p] - m); sum += ex[p]; }
#pragma unroll
    for (int p = 0; p < 4; p++) {
      const float g = ex[p] / sum;
      sm.u.b.gvL[r][tk * 4 + p] = g;
      sm.u.b.giL[r][tk * 4 + p] = idx[p];
      atomicAdd(&sm.u.b.impL[tk * 16 + idx[p]], g);
      atomicAdd(&sm.u.b.loadL[tk * 16 + idx[p]], 1.f);
    }
  }
  __syncthreads();

  // ---- cooperative f64 rescue for near-ties ----
  const int nr = sm.u.b.nresc;
  for (int i = 0; i < nr; i++) {
    const int st = sm.u.b.resc[i];
    const int r = st >> 2, tk = st & 3;
    {
      const int e = tid >> 4, part = tid & 15;
      const float* xr2 = &x[(size_t)(b0 + r) * 512];
      const float* wgc = &wg[(size_t)tk * 8192 + e];
      double a = 0.0;
      for (int d = part * 32; d < part * 32 + 32; d++)
        a += (double)xr2[d] * (double)wgc[(size_t)d * 16];
#pragma unroll
      for (int off = 1; off < 16; off <<= 1) a += __shfl_xor(a, off);
      if (part == 0) sm.u.b.resL[e] = a + (double)bg[tk * 16 + e];
    }
    __syncthreads();
    if (tid == 0) {
      for (int p = 0; p < 4; p++) {
        sm.u.b.impL[tk * 16 + sm.u.b.giL[r][tk * 4 + p]] -= sm.u.b.gvL[r][tk * 4 + p];
        sm.u.b.loadL[tk * 16 + sm.u.b.giL[r][tk * 4 + p]] -= 1.f;
      }
      unsigned used = 0;
      int idx[4]; float val[4];
      for (int p = 0; p < 4; p++) {
        double best = -1e300; int bi = 0;
        for (int e2 = 0; e2 < 16; e2++) {
          if ((used >> e2) & 1u) continue;
          const double ve = sm.u.b.resL[e2];
          if (ve > best) { best = ve; bi = e2; }
        }
        idx[p] = bi; val[p] = (float)best; used |= 1u << bi;
      }
      const float m = val[0];
      float ex[4], sum = 0.f;
      for (int p = 0; p < 4; p++) { ex[p] = __expf(val[p] - m); sum += ex[p]; }
      for (int p = 0; p < 4; p++) {
        const float g = ex[p] / sum;
        sm.u.b.gvL[r][tk * 4 + p] = g;
        sm.u.b.giL[r][tk * 4 + p] = idx[p];
        sm.u.b.impL[tk * 16 + idx[p]] += g;
        sm.u.b.loadL[tk * 16 + idx[p]] += 1.f;
      }
    }
    __syncthreads();
  }
  if (tid < 48) {
    atomicAdd(&acc_imp[tid], sm.u.b.impL[tid]);
    atomicAdd(&acc_load[tid], sm.u.b.loadL[tid]);
  }

  // ---- combine: 2 barrier-free passes of 16 rows x 16 outputs ----
#pragma unroll
  for (int p2 = 0; p2 < 2; ++p2) {
    const int rl = p2 * 16 + (tid >> 4), o = tid & 15;
    const int osw = (rl & 3) << 2;
#pragma unroll
    for (int tk = 0; tk < TT; tk++) {
      float y = 0.f;
#pragma unroll
      for (int p = 0; p < 4; p++)
        y += sm.u.b.gvL[rl][tk * 4 + p] *
             h2f(sm.u.b.eoL[rl][sm.u.b.giL[rl][tk * 4 + p]][o ^ osw]);
      out[((size_t)tk * BSZ + b0 + rl) * OO + o] = y;
    }
  }
}

// Parallel k_final: 48 threads load+shuffle-reduce.
__global__ void k_final(const float* __restrict__ acc_imp,
                        const float* __restrict__ acc_load,
                        const float* __restrict__ rz_acc,
                        float* __restrict__ out_tail) {
  const int tid = threadIdx.x;           // one wave (64 lanes)
  const int t = tid >> 4, e = tid & 15;  // t=0..2 active, t=3 idle
  const bool act = t < 3;
  const float impf = act ? acc_imp[t * 16 + e] : 0.f;
  const float ldf  = act ? acc_load[t * 16 + e] : 0.f;
  const double imp = impf, ld = ldf;
  double si = imp, sl = ld, dot = imp * ld;
#pragma unroll
  for (int off = 1; off < 16; off <<= 1) {
    si += __shfl_xor(si, off);
    sl += __shfl_xor(sl, off);
    dot += __shfl_xor(dot, off);
  }
  const double mi = si / 16.0, ml = sl / 16.0;
  double vi = (imp - mi) * (imp - mi), vl = (ld - ml) * (ld - ml);
#pragma unroll
  for (int off = 1; off < 16; off <<= 1) {
    vi += __shfl_xor(vi, off);
    vl += __shfl_xor(vl, off);
  }
  const double lb = (vi / 15.0 / (mi * mi + 1e-10) + vl / 15.0 / (ml * ml + 1e-10)) * 0.01
                  + 16.0 * dot / (double)BSZ * 0.01;
  const double l0 = __shfl(lb, 0), l1 = __shfl(lb, 16), l2 = __shfl(lb, 32);
  if (tid == 0) {
    out_tail[0] = (float)(l0 + l1 + l2);
    out_tail[1] = (float)(3.0 * (rz_acc[0] / (double)BSZ) * 0.001);
  }
}

extern "C" void kernel_launch(void* const* d_in, const int* in_sizes, int n_in,
                              void* d_out, int out_size, void* d_ws, size_t ws_size,
                              hipStream_t stream) {
  const float* x  = (const float*)d_in[0];
  const float* wg = (const float*)d_in[1];
  const float* bg = (const float*)d_in[2];
  const float* W1 = (const float*)d_in[3];
  const float* b1 = (const float*)d_in[4];
  const float* W2 = (const float*)d_in[5];
  const float* b2 = (const float*)d_in[6];
  const float* W3 = (const float*)d_in[7];
  const float* b3 = (const float*)d_in[8];
  float* out = (float*)d_out;

  char* wsb = (char*)d_ws;
  unsigned short* Wf  = (unsigned short*)wsb;            // 327,680 B
  unsigned short* W2A = (unsigned short*)(wsb + 327680); // 8,192 B
  unsigned short* W3A = (unsigned short*)(wsb + 335872); // 8,192 B
  float* acc = (float*)(wsb + 344064);                   // 97 floats

  k_prepw<<<dim3(640), dim3(256), 0, stream>>>(W1, wg, W2, W3, Wf, W2A, W3A, acc);
  k_fused<<<dim3(BSZ / 32), dim3(256), 0, stream>>>(
      x, Wf, b1, bg, wg, W2A, b2, W3A, b3, out, acc, acc + 48, acc + 96);
  k_final<<<dim3(1), dim3(64), 0, stream>>>(acc, acc + 48, acc + 96,
                                            out + (size_t)TT * BSZ * OO);
}